// Round 1
// 1193.892 us; speedup vs baseline: 3.1523x; 3.1523x over previous
//
#include <hip/hip_runtime.h>
#include <hip/hip_bf16.h>

#define N_NODES 50000
#define N_EDGES 400000
#define SLOPE 0.2f

typedef __attribute__((ext_vector_type(8))) short bf16x8;   // 8 bf16 = 4 VGPR (MFMA A/B frag)
typedef __attribute__((ext_vector_type(4))) float f32x4;    // MFMA C/D frag
#define MFMA_BF16 __builtin_amdgcn_mfma_f32_16x16x32_bf16

static __device__ __forceinline__ float lrelu(float x) { return x >= 0.f ? x : SLOPE * x; }
static __device__ __forceinline__ float b2f(__hip_bfloat16 x) { return __bfloat162float(x); }
static __device__ __forceinline__ float u2f(unsigned short u) {
    union { unsigned short u; __hip_bfloat16 b; } cv; cv.u = u; return __bfloat162float(cv.b);
}
static __device__ __forceinline__ unsigned short f2bf(float x) {
    union { __hip_bfloat16 b; unsigned short u; } cv; cv.b = __float2bfloat16(x); return cv.u;
}
static __device__ __forceinline__ int clampi(int v, int lo, int hi) {
    return v < lo ? lo : (v > hi ? hi : v);
}
// dual-dtype float load: isb ? bf16 : f32
static __device__ __forceinline__ float ldF(const void* __restrict__ p, size_t i, bool isb) {
    return isb ? b2f(((const __hip_bfloat16*)p)[i]) : ((const float*)p)[i];
}
// dual-width index load: i64 ? int64 : int32
static __device__ __forceinline__ int ldI(const void* __restrict__ p, size_t i, bool i64) {
    return i64 ? (int)(((const long long*)p)[i]) : ((const int*)p)[i];
}

// ---------------- K0: dtype detection ----------------------------------------------------
__global__ void k_detect(const void* __restrict__ nf, const void* __restrict__ eidx,
                         int* __restrict__ flags)
{
    int t = threadIdx.x;  // 64 threads
    float x = b2f(((const __hip_bfloat16*)nf)[2 * t]);
    bool bad = !(x == x) || fabsf(x) > 1e4f;
    unsigned long long fmask = __ballot(bad);
    int v = ((const int*)eidx)[2 * t + 1];
    unsigned long long imask = __ballot(v != 0);
    if (t == 0) {
        flags[0] = (fmask == 0ull) ? 1 : 0;  // 1 => floats are bf16
        flags[1] = (imask == 0ull) ? 1 : 0;  // 1 => ints are int64
    }
}

// ---------------- K0b: weight prep (transpose + bf16-ify) --------------------------------
// WeaT/WetT: [128][64]  (WT[c][k] = W[k][c]), Wu2T: [128][128] from Wup rows 128..255,
// WatT: [16][512] with rows 8..15 zeroed (lets scores use a full 16-col MFMA tile).
__global__ __launch_bounds__(256) void k_wprep(
    const void* __restrict__ Wea, const void* __restrict__ Wet,
    const void* __restrict__ Wup, const void* __restrict__ Wat,
    unsigned short* __restrict__ WeaT, unsigned short* __restrict__ WetT,
    unsigned short* __restrict__ Wu2T, unsigned short* __restrict__ WatT,
    const int* __restrict__ flags)
{
    const bool isb = flags[0] != 0;
    int i = blockIdx.x * blockDim.x + threadIdx.x;
    if (i < 128 * 64) {
        int c = i >> 6, k = i & 63;
        WeaT[i] = f2bf(ldF(Wea, (size_t)k * 128 + c, isb));
        WetT[i] = f2bf(ldF(Wet, (size_t)k * 128 + c, isb));
    }
    if (i < 128 * 128) {
        int c = i >> 7, k = i & 127;
        Wu2T[i] = f2bf(ldF(Wup, (size_t)(128 + k) * 128 + c, isb));
    }
    if (i < 16 * 512) {
        int c = i >> 9, k = i & 511;
        WatT[i] = (c < 8) ? f2bf(ldF(Wat, (size_t)k * 8 + c, isb)) : (unsigned short)0;
    }
}

// ---------------- K1: typed node embedding ------------------------------------------------
__global__ __launch_bounds__(128) void k_node_emb(
    const void* __restrict__ nf, const void* __restrict__ ntype,
    const void* __restrict__ Wn, __hip_bfloat16* __restrict__ node_emb,
    const int* __restrict__ flags)
{
    const bool isb = flags[0] != 0, i64 = flags[1] != 0;
    int n = blockIdx.x, t = threadIdx.x;
    __shared__ float x[256];
    x[t]       = ldF(nf, (size_t)n * 256 + t, isb);
    x[128 + t] = ldF(nf, (size_t)n * 256 + 128 + t, isb);
    __syncthreads();
    int ty = clampi(ldI(ntype, n, i64), 0, 2);
    float acc = 0.f;
    if (isb) {
        const __hip_bfloat16* W = (const __hip_bfloat16*)Wn + (size_t)ty * 256 * 128;
        #pragma unroll 4
        for (int i = 0; i < 256; ++i) acc += x[i] * b2f(W[(size_t)i * 128 + t]);
    } else {
        const float* W = (const float*)Wn + (size_t)ty * 256 * 128;
        #pragma unroll 4
        for (int i = 0; i < 256; ++i) acc += x[i] * W[(size_t)i * 128 + t];
    }
    node_emb[(size_t)n * 128 + t] = __float2bfloat16(acc);
}

// ---------------- K2: fused per-edge MFMA kernel ------------------------------------------
// 32 edges/block, 256 threads = 4 waves; wave w -> (m = w&1 edge-half, nh = w>>1 col-half).
// Stage 1: attr_emb/type_emb = lrelu(EA/ET[32,64] @ W[64,128])  -> LDS (bf16, padded)
// Stage 2: ap[32,128] = attr_emb @ Wu2                          -> global bf16
// Stage 3: scores[32,8] = lrelu([tar|ae|te|src][32,512] @ Wat)  -> global f32
// A- and B-fragments use the SAME (lane>>4, elem)->k mapping, so result is k-perm-robust.
__global__ __launch_bounds__(256) void k_edge(
    const void* __restrict__ eattr, const void* __restrict__ etype,
    const void* __restrict__ eidx, const unsigned short* __restrict__ node_emb_u,
    const unsigned short* __restrict__ WeaT, const unsigned short* __restrict__ WetT,
    const unsigned short* __restrict__ Wu2T, const unsigned short* __restrict__ WatT,
    float* __restrict__ scores, unsigned short* ap, const int* __restrict__ flags)
{
    const bool isb = flags[0] != 0, i64 = flags[1] != 0;
    const int t = threadIdx.x;
    const int lane = t & 63, wid = t >> 6;
    const int m = wid & 1, nh = wid >> 1;
    const int lr = lane & 15, lg = lane >> 4;
    const int e0 = blockIdx.x * 32;

    // padded row stride 136 bf16 (=272B): bank = (4*row + 4*kgrp) % 32 -> worst 2-way (free)
    __shared__ int s_idx[64];
    __shared__ __align__(16) unsigned short s_tar[32 * 136];
    __shared__ __align__(16) unsigned short s_ae [32 * 136];
    __shared__ __align__(16) unsigned short s_te [32 * 136];
    __shared__ __align__(16) unsigned short s_src[32 * 136];

    if (t < 64) {
        int e = e0 + (t & 31);
        int v = (t < 32) ? ldI(eidx, (size_t)e, i64)
                         : ldI(eidx, (size_t)N_EDGES + e, i64);
        s_idx[t] = clampi(v, 0, N_NODES - 1);   // [0..31]=src, [32..63]=tar
    }
    __syncthreads();

    // gather src/tar embeddings (bf16 raw copy, ushort2 granularity)
    for (int i = t; i < 32 * 64; i += 256) {
        int r = i >> 6, c2 = i & 63;
        *(ushort2*)&s_src[r * 136 + c2 * 2] =
            *(const ushort2*)(node_emb_u + (size_t)s_idx[r] * 128 + c2 * 2);
        *(ushort2*)&s_tar[r * 136 + c2 * 2] =
            *(const ushort2*)(node_emb_u + (size_t)s_idx[32 + r] * 128 + c2 * 2);
    }

    // ---- Stage 1: attr_emb / type_emb ----------------------------------
    bf16x8 Aea[2], Aet[2];
    const int arow = e0 + m * 16 + lr;
    #pragma unroll
    for (int ks = 0; ks < 2; ++ks) {
        const int koff = ks * 32 + lg * 8;
        if (isb) {
            Aea[ks] = *(const bf16x8*)((const unsigned short*)eattr + (size_t)arow * 64 + koff);
            Aet[ks] = *(const bf16x8*)((const unsigned short*)etype + (size_t)arow * 64 + koff);
        } else {
            const float* pa = (const float*)eattr + (size_t)arow * 64 + koff;
            const float* pt = (const float*)etype + (size_t)arow * 64 + koff;
            float4 a0 = *(const float4*)pa, a1 = *(const float4*)(pa + 4);
            float4 t0 = *(const float4*)pt, t1 = *(const float4*)(pt + 4);
            bf16x8 va, vt;
            va[0] = (short)f2bf(a0.x); va[1] = (short)f2bf(a0.y);
            va[2] = (short)f2bf(a0.z); va[3] = (short)f2bf(a0.w);
            va[4] = (short)f2bf(a1.x); va[5] = (short)f2bf(a1.y);
            va[6] = (short)f2bf(a1.z); va[7] = (short)f2bf(a1.w);
            vt[0] = (short)f2bf(t0.x); vt[1] = (short)f2bf(t0.y);
            vt[2] = (short)f2bf(t0.z); vt[3] = (short)f2bf(t0.w);
            vt[4] = (short)f2bf(t1.x); vt[5] = (short)f2bf(t1.y);
            vt[6] = (short)f2bf(t1.z); vt[7] = (short)f2bf(t1.w);
            Aea[ks] = va; Aet[ks] = vt;
        }
    }
    f32x4 acc_a[4], acc_b[4];
    #pragma unroll
    for (int ct = 0; ct < 4; ++ct) { acc_a[ct] = (f32x4)(0.f); acc_b[ct] = (f32x4)(0.f); }
    #pragma unroll
    for (int ct = 0; ct < 4; ++ct) {
        const int crow = nh * 64 + ct * 16 + lr;      // WT row == output column
        #pragma unroll
        for (int ks = 0; ks < 2; ++ks) {
            const int koff = ks * 32 + lg * 8;
            bf16x8 Bea = *(const bf16x8*)(WeaT + (size_t)crow * 64 + koff);
            bf16x8 Bet = *(const bf16x8*)(WetT + (size_t)crow * 64 + koff);
            acc_a[ct] = MFMA_BF16(Aea[ks], Bea, acc_a[ct], 0, 0, 0);
            acc_b[ct] = MFMA_BF16(Aet[ks], Bet, acc_b[ct], 0, 0, 0);
        }
    }
    // C/D layout (verified): col = lane&15, row = (lane>>4)*4 + j
    #pragma unroll
    for (int ct = 0; ct < 4; ++ct) {
        const int col = nh * 64 + ct * 16 + lr;
        #pragma unroll
        for (int j = 0; j < 4; ++j) {
            const int row = m * 16 + lg * 4 + j;
            s_ae[row * 136 + col] = f2bf(lrelu(acc_a[ct][j]));
            s_te[row * 136 + col] = f2bf(lrelu(acc_b[ct][j]));
        }
    }
    __syncthreads();

    // ---- Stage 2: ap = attr_emb @ Wu2 ----------------------------------
    if (ap != nullptr) {
        bf16x8 A2[4];
        #pragma unroll
        for (int ks = 0; ks < 4; ++ks)
            A2[ks] = *(const bf16x8*)&s_ae[(m * 16 + lr) * 136 + ks * 32 + lg * 8];
        f32x4 acc2[4];
        #pragma unroll
        for (int ct = 0; ct < 4; ++ct) acc2[ct] = (f32x4)(0.f);
        #pragma unroll
        for (int ct = 0; ct < 4; ++ct) {
            const int crow = nh * 64 + ct * 16 + lr;
            #pragma unroll
            for (int ks = 0; ks < 4; ++ks) {
                bf16x8 B2 = *(const bf16x8*)(Wu2T + (size_t)crow * 128 + ks * 32 + lg * 8);
                acc2[ct] = MFMA_BF16(A2[ks], B2, acc2[ct], 0, 0, 0);
            }
        }
        #pragma unroll
        for (int ct = 0; ct < 4; ++ct) {
            const int col = nh * 64 + ct * 16 + lr;
            #pragma unroll
            for (int j = 0; j < 4; ++j) {
                const int e = e0 + m * 16 + lg * 4 + j;
                ap[(size_t)e * 128 + col] = f2bf(acc2[ct][j]);
            }
        }
    }

    // ---- Stage 3: scores (waves nh==0; K=512 over [tar|ae|te|src]) -----
    if (nh == 0) {
        f32x4 accS = (f32x4)(0.f);
        #pragma unroll
        for (int seg = 0; seg < 4; ++seg) {
            const unsigned short* sb = (seg == 0) ? s_tar : (seg == 1) ? s_ae
                                     : (seg == 2) ? s_te : s_src;
            #pragma unroll
            for (int ks = 0; ks < 4; ++ks) {
                bf16x8 A = *(const bf16x8*)&sb[(m * 16 + lr) * 136 + ks * 32 + lg * 8];
                bf16x8 B = *(const bf16x8*)(WatT + (size_t)lr * 512 + seg * 128 + ks * 32 + lg * 8);
                accS = MFMA_BF16(A, B, accS, 0, 0, 0);
            }
        }
        if (lr < 8) {
            #pragma unroll
            for (int j = 0; j < 4; ++j) {
                const int e = e0 + m * 16 + lg * 4 + j;
                scores[(size_t)e * 8 + lr] = lrelu(accS[j]);
            }
        }
    }
}

// ---------------- K3: CSR build over src --------------------------------------------------
__global__ void k_hist(const void* __restrict__ eidx, int* __restrict__ counts,
                       const int* __restrict__ flags)
{
    const bool i64 = flags[1] != 0;
    int e = blockIdx.x * blockDim.x + threadIdx.x;
    if (e < N_EDGES) atomicAdd(&counts[clampi(ldI(eidx, e, i64), 0, N_NODES - 1)], 1);
}

// parallel 3-pass exclusive scan (replaces single-block serial scan)
__global__ __launch_bounds__(256) void k_scan1(const int* __restrict__ counts,
                                               int* __restrict__ offsets, int* __restrict__ bsum)
{
    __shared__ int buf[256];
    int b = blockIdx.x, t = threadIdx.x, i = b * 256 + t;
    int v = (i < N_NODES) ? counts[i] : 0;
    buf[t] = v;
    __syncthreads();
    for (int d = 1; d < 256; d <<= 1) {
        int add = (t >= d) ? buf[t - d] : 0;
        __syncthreads();
        buf[t] += add;
        __syncthreads();
    }
    if (i < N_NODES) offsets[i] = buf[t] - v;
    if (t == 255) bsum[b] = buf[255];
}
__global__ __launch_bounds__(256) void k_scan2(int* __restrict__ bsum, int nb)
{
    __shared__ int buf[256];
    int t = threadIdx.x;
    int v = (t < nb) ? bsum[t] : 0;
    buf[t] = v;
    __syncthreads();
    for (int d = 1; d < 256; d <<= 1) {
        int add = (t >= d) ? buf[t - d] : 0;
        __syncthreads();
        buf[t] += add;
        __syncthreads();
    }
    if (t < nb) bsum[t] = buf[t] - v;
}
__global__ __launch_bounds__(256) void k_scan3(int* __restrict__ offsets,
                                               const int* __restrict__ bsum)
{
    int i = blockIdx.x * 256 + threadIdx.x;
    if (i < N_NODES) offsets[i] += bsum[i >> 8];
}

__global__ void k_scatter(const void* __restrict__ eidx, const int* __restrict__ offsets,
                          int* __restrict__ fill, int* __restrict__ perm,
                          const int* __restrict__ flags)
{
    const bool i64 = flags[1] != 0;
    int e = blockIdx.x * blockDim.x + threadIdx.x;
    if (e >= N_EDGES) return;
    int s = clampi(ldI(eidx, e, i64), 0, N_NODES - 1);
    int p = atomicAdd(&fill[s], 1);
    perm[offsets[s] + p] = e;
}

// ---------------- K4: segment softmax stats; pass3 writes attn IN-PLACE into scores -------
__global__ void k_stats(const float* scores, const int* __restrict__ offsets,
                        const int* __restrict__ counts, const int* __restrict__ perm,
                        float* __restrict__ stats, float* attn, int write_attn)
{
    int tid = blockIdx.x * blockDim.x + threadIdx.x;
    if (tid >= N_NODES * 8) return;
    int n = tid >> 3, h = tid & 7;
    int off = offsets[n], deg = counts[n];
    if (deg == 0) { stats[n * 16 + h] = 0.f; stats[n * 16 + 8 + h] = 1.f; return; }
    float m = -1e30f;
    for (int j = 0; j < deg; ++j) {
        int e = clampi(perm[off + j], 0, N_EDGES - 1);
        m = fmaxf(m, scores[(size_t)e * 8 + h]);
    }
    float d = 0.f;
    for (int j = 0; j < deg; ++j) {
        int e = clampi(perm[off + j], 0, N_EDGES - 1);
        d += expf(scores[(size_t)e * 8 + h] - m);
    }
    stats[n * 16 + h] = m;
    stats[n * 16 + 8 + h] = (d > 0.f) ? d : 1.f;
    if (write_attn) {
        float inv = (d > 0.f) ? 1.f / d : 0.f;
        for (int j = 0; j < deg; ++j) {
            int e = clampi(perm[off + j], 0, N_EDGES - 1);
            attn[(size_t)e * 8 + h] = expf(scores[(size_t)e * 8 + h] - m) * inv;
        }
    }
}

// ---------------- K5: lean per-node aggregation (big-ws path) -----------------------------
// out[n,h,:] = sum_e attn[e,h] * lrelu(base[n] + ap[e]);  base = node_emb[n] @ Wup[0:128]
__global__ __launch_bounds__(128) void k_aggr2(
    const unsigned short* __restrict__ node_emb_u, const float* __restrict__ attn,
    const unsigned short* __restrict__ ap, const int* __restrict__ offsets,
    const int* __restrict__ counts, const int* __restrict__ perm,
    const void* __restrict__ Wup, void* __restrict__ out, const int* __restrict__ flags)
{
    const bool isb = flags[0] != 0;
    int n = blockIdx.x, t = threadIdx.x;
    __shared__ float xe[128];
    xe[t] = u2f(node_emb_u[(size_t)n * 128 + t]);
    __syncthreads();
    float base = 0.f;
    if (isb) {
        const __hip_bfloat16* W = (const __hip_bfloat16*)Wup;
        #pragma unroll 4
        for (int i = 0; i < 128; ++i) base += xe[i] * b2f(W[(size_t)i * 128 + t]);
    } else {
        const float* W = (const float*)Wup;
        #pragma unroll 4
        for (int i = 0; i < 128; ++i) base += xe[i] * W[(size_t)i * 128 + t];
    }
    float acc[8];
    #pragma unroll
    for (int h = 0; h < 8; ++h) acc[h] = 0.f;
    int off = offsets[n], deg = counts[n];
    for (int j = 0; j < deg; ++j) {
        int e = clampi(perm[off + j], 0, N_EDGES - 1);
        float msg = lrelu(base + u2f(ap[(size_t)e * 128 + t]));
        const float* at = attn + (size_t)e * 8;   // one 32B line, broadcast to all lanes
        #pragma unroll
        for (int h = 0; h < 8; ++h) acc[h] += at[h] * msg;
    }
    if (isb) {
        __hip_bfloat16* o = (__hip_bfloat16*)out;
        #pragma unroll
        for (int h = 0; h < 8; ++h)
            o[(size_t)n * 1024 + h * 128 + t] = __float2bfloat16(acc[h]);
    } else {
        float* o = (float*)out;
        #pragma unroll
        for (int h = 0; h < 8; ++h)
            o[(size_t)n * 1024 + h * 128 + t] = acc[h];
    }
}

// ---------------- K5-fallback: original aggregation (small-ws path) -----------------------
__global__ __launch_bounds__(128) void k_aggr_old(
    const __hip_bfloat16* __restrict__ node_emb, const float* __restrict__ stats,
    const float* __restrict__ scores, const int* __restrict__ offsets,
    const int* __restrict__ counts, const int* __restrict__ perm,
    const void* __restrict__ eattr, const void* __restrict__ Wea,
    const void* __restrict__ Wup, void* __restrict__ out,
    const int* __restrict__ flags)
{
    const bool isb = flags[0] != 0;
    int n = blockIdx.x, t = threadIdx.x;
    __shared__ float xe[128], ea[64], ae[128], attn_s[8], mh[8], invd[8];
    xe[t] = b2f(node_emb[(size_t)n * 128 + t]);
    if (t < 8) {
        mh[t] = stats[n * 16 + t];
        float dn = stats[n * 16 + 8 + t];
        invd[t] = (dn > 0.f) ? 1.f / dn : 0.f;
    }
    __syncthreads();
    float base = 0.f;
    if (isb) {
        const __hip_bfloat16* W = (const __hip_bfloat16*)Wup;
        #pragma unroll 4
        for (int i = 0; i < 128; ++i) base += xe[i] * b2f(W[(size_t)i * 128 + t]);
    } else {
        const float* W = (const float*)Wup;
        #pragma unroll 4
        for (int i = 0; i < 128; ++i) base += xe[i] * W[(size_t)i * 128 + t];
    }
    float acc[8];
    #pragma unroll
    for (int h = 0; h < 8; ++h) acc[h] = 0.f;
    int off = offsets[n], deg = counts[n];
    for (int j = 0; j < deg; ++j) {
        int e = clampi(perm[off + j], 0, N_EDGES - 1);
        if (t < 64) ea[t] = ldF(eattr, (size_t)e * 64 + t, isb);
        if (t < 8)  attn_s[t] = expf(scores[(size_t)e * 8 + t] - mh[t]) * invd[t];
        __syncthreads();
        float a = 0.f;
        if (isb) {
            const __hip_bfloat16* WA = (const __hip_bfloat16*)Wea;
            #pragma unroll 4
            for (int k = 0; k < 64; ++k) a += ea[k] * b2f(WA[(size_t)k * 128 + t]);
        } else {
            const float* WA = (const float*)Wea;
            #pragma unroll 4
            for (int k = 0; k < 64; ++k) a += ea[k] * WA[(size_t)k * 128 + t];
        }
        ae[t] = lrelu(a);
        __syncthreads();
        float msg = base;
        if (isb) {
            const __hip_bfloat16* W = (const __hip_bfloat16*)Wup;
            #pragma unroll 4
            for (int i = 0; i < 128; ++i) msg += ae[i] * b2f(W[(size_t)(128 + i) * 128 + t]);
        } else {
            const float* W = (const float*)Wup;
            #pragma unroll 4
            for (int i = 0; i < 128; ++i) msg += ae[i] * W[(size_t)(128 + i) * 128 + t];
        }
        msg = lrelu(msg);
        #pragma unroll
        for (int h = 0; h < 8; ++h) acc[h] += attn_s[h] * msg;
        __syncthreads();
    }
    if (isb) {
        __hip_bfloat16* o = (__hip_bfloat16*)out;
        #pragma unroll
        for (int h = 0; h < 8; ++h)
            o[(size_t)n * 1024 + h * 128 + t] = __float2bfloat16(acc[h]);
    } else {
        float* o = (float*)out;
        #pragma unroll
        for (int h = 0; h < 8; ++h)
            o[(size_t)n * 1024 + h * 128 + t] = acc[h];
    }
}

// ---------------- launcher ----------------------------------------------------------------
static inline size_t alignup(size_t x, size_t a) { return (x + a - 1) & ~(a - 1); }

extern "C" void kernel_launch(void* const* d_in, const int* in_sizes, int n_in,
                              void* d_out, int out_size, void* d_ws, size_t ws_size,
                              hipStream_t stream)
{
    const void* nf   = d_in[0];
    const void* eidx = d_in[1];
    const void* eatt = d_in[2];
    const void* etyp = d_in[3];
    const void* ntyp = d_in[4];
    // d_in[5] edge_type_list: unused by the reference
    const void* Wn   = d_in[6];
    const void* Wea  = d_in[7];
    const void* Wet  = d_in[8];
    const void* Wup  = d_in[9];
    const void* Wat  = d_in[10];

    // workspace layout
    char* w = (char*)d_ws;
    size_t off = 0;
    int* flags = (int*)w;                                   off = 16;
    unsigned short* node_emb = (unsigned short*)(w + off);  off += (size_t)N_NODES * 128 * 2;
    float* scores  = (float*)(w + off);                     off += (size_t)N_EDGES * 8 * 4;
    float* stats   = (float*)(w + off);                     off += (size_t)N_NODES * 16 * 4;
    int*   counts  = (int*)(w + off);                       off += (size_t)N_NODES * 4;
    int*   offsets = (int*)(w + off);                       off += (size_t)(N_NODES + 1) * 4;
    int*   fill    = (int*)(w + off);                       off += (size_t)N_NODES * 4;
    int*   perm    = (int*)(w + off);                       off += (size_t)N_EDGES * 4;
    int*   bsum    = (int*)(w + off);                       off += 256 * 4;
    off = alignup(off, 16);
    unsigned short* WeaT = (unsigned short*)(w + off);      off += 128 * 64 * 2;
    unsigned short* WetT = (unsigned short*)(w + off);      off += 128 * 64 * 2;
    unsigned short* Wu2T = (unsigned short*)(w + off);      off += 128 * 128 * 2;
    unsigned short* WatT = (unsigned short*)(w + off);      off += 16 * 512 * 2;
    off = alignup(off, 16);
    unsigned short* ap = (unsigned short*)(w + off);
    const size_t need_ap = off + (size_t)N_EDGES * 128 * 2;   // ~134 MB total
    const bool big = ws_size >= need_ap;

    hipMemsetAsync(counts, 0, N_NODES * sizeof(int), stream);
    hipMemsetAsync(fill, 0, N_NODES * sizeof(int), stream);

    const int SCAN_BLKS = (N_NODES + 255) / 256;

    k_detect<<<1, 64, 0, stream>>>(nf, eidx, flags);
    k_wprep<<<64, 256, 0, stream>>>(Wea, Wet, Wup, Wat, WeaT, WetT, Wu2T, WatT, flags);
    k_node_emb<<<N_NODES, 128, 0, stream>>>(nf, ntyp, Wn, (__hip_bfloat16*)node_emb, flags);
    k_edge<<<N_EDGES / 32, 256, 0, stream>>>(eatt, etyp, eidx, node_emb,
                                             WeaT, WetT, Wu2T, WatT,
                                             scores, big ? ap : (unsigned short*)nullptr, flags);
    k_hist<<<(N_EDGES + 255) / 256, 256, 0, stream>>>(eidx, counts, flags);
    k_scan1<<<SCAN_BLKS, 256, 0, stream>>>(counts, offsets, bsum);
    k_scan2<<<1, 256, 0, stream>>>(bsum, SCAN_BLKS);
    k_scan3<<<SCAN_BLKS, 256, 0, stream>>>(offsets, bsum);
    k_scatter<<<(N_EDGES + 255) / 256, 256, 0, stream>>>(eidx, offsets, fill, perm, flags);
    k_stats<<<(N_NODES * 8 + 255) / 256, 256, 0, stream>>>(scores, offsets, counts, perm,
                                                           stats, scores, big ? 1 : 0);
    if (big)
        k_aggr2<<<N_NODES, 128, 0, stream>>>(node_emb, scores, ap, offsets, counts, perm,
                                             Wup, d_out, flags);
    else
        k_aggr_old<<<N_NODES, 128, 0, stream>>>((const __hip_bfloat16*)node_emb, stats, scores,
                                                offsets, counts, perm, eatt, Wea, Wup,
                                                d_out, flags);
}

// Round 2
// 903.723 us; speedup vs baseline: 4.1645x; 1.3211x over previous
//
#include <hip/hip_runtime.h>
#include <hip/hip_bf16.h>

#define N_NODES 50000
#define N_EDGES 400000
#define SLOPE 0.2f

typedef __attribute__((ext_vector_type(8))) short bf16x8;   // 8 bf16 = 4 VGPR (MFMA A/B frag)
typedef __attribute__((ext_vector_type(4))) float f32x4;    // MFMA C/D frag
#define MFMA_BF16 __builtin_amdgcn_mfma_f32_16x16x32_bf16

static __device__ __forceinline__ float lrelu(float x) { return x >= 0.f ? x : SLOPE * x; }
static __device__ __forceinline__ float b2f(__hip_bfloat16 x) { return __bfloat162float(x); }
static __device__ __forceinline__ float u2f(unsigned short u) {
    union { unsigned short u; __hip_bfloat16 b; } cv; cv.u = u; return __bfloat162float(cv.b);
}
static __device__ __forceinline__ unsigned short f2bf(float x) {
    union { __hip_bfloat16 b; unsigned short u; } cv; cv.b = __float2bfloat16(x); return cv.u;
}
static __device__ __forceinline__ int clampi(int v, int lo, int hi) {
    return v < lo ? lo : (v > hi ? hi : v);
}
// dual-dtype float load: isb ? bf16 : f32
static __device__ __forceinline__ float ldF(const void* __restrict__ p, size_t i, bool isb) {
    return isb ? b2f(((const __hip_bfloat16*)p)[i]) : ((const float*)p)[i];
}
// dual-width index load: i64 ? int64 : int32
static __device__ __forceinline__ int ldI(const void* __restrict__ p, size_t i, bool i64) {
    return i64 ? (int)(((const long long*)p)[i]) : ((const int*)p)[i];
}

// ---------------- K0: dtype detection ----------------------------------------------------
__global__ void k_detect(const void* __restrict__ nf, const void* __restrict__ eidx,
                         int* __restrict__ flags)
{
    int t = threadIdx.x;  // 64 threads
    float x = b2f(((const __hip_bfloat16*)nf)[2 * t]);
    bool bad = !(x == x) || fabsf(x) > 1e4f;
    unsigned long long fmask = __ballot(bad);
    int v = ((const int*)eidx)[2 * t + 1];
    unsigned long long imask = __ballot(v != 0);
    if (t == 0) {
        flags[0] = (fmask == 0ull) ? 1 : 0;  // 1 => floats are bf16
        flags[1] = (imask == 0ull) ? 1 : 0;  // 1 => ints are int64
    }
}

// ---------------- K0b: weight prep (transpose + bf16-ify) --------------------------------
// All *T layouts are [out_col][k] bf16 so B-fragments are contiguous 16B loads with the
// same k-mapping as A-fragments (k-permutation-robust).
// WnT[3][128][256]; WeaT/WetT[128][64]; Wu1T/Wu2T[128][128];
// WatMidT[16][256] (k = [ae|te], cols 8..15 zero); WatTS[16][128] (cols 0..7 = Wat tar rows,
// cols 8..15 = Wat src rows).
__global__ __launch_bounds__(256) void k_wprep(
    const void* __restrict__ Wn, const void* __restrict__ Wea, const void* __restrict__ Wet,
    const void* __restrict__ Wup, const void* __restrict__ Wat,
    unsigned short* __restrict__ WnT, unsigned short* __restrict__ WeaT,
    unsigned short* __restrict__ WetT, unsigned short* __restrict__ Wu1T,
    unsigned short* __restrict__ Wu2T, unsigned short* __restrict__ WatMidT,
    unsigned short* __restrict__ WatTS, const int* __restrict__ flags)
{
    const bool isb = flags[0] != 0;
    int i = blockIdx.x * 256 + threadIdx.x;
    if (i < 3 * 128 * 256) {
        int ty = i >> 15, rem = i & 32767, c = rem >> 8, k = rem & 255;
        WnT[i] = f2bf(ldF(Wn, ((size_t)ty * 256 + k) * 128 + c, isb));
    }
    if (i < 128 * 128) {
        int c = i >> 7, k = i & 127;
        Wu1T[i] = f2bf(ldF(Wup, (size_t)k * 128 + c, isb));
        Wu2T[i] = f2bf(ldF(Wup, (size_t)(128 + k) * 128 + c, isb));
    }
    if (i < 128 * 64) {
        int c = i >> 6, k = i & 63;
        WeaT[i] = f2bf(ldF(Wea, (size_t)k * 128 + c, isb));
        WetT[i] = f2bf(ldF(Wet, (size_t)k * 128 + c, isb));
    }
    if (i < 16 * 256) {
        int c = i >> 8, k = i & 255;
        WatMidT[i] = (c < 8) ? f2bf(ldF(Wat, (size_t)(128 + k) * 8 + c, isb)) : (unsigned short)0;
    }
    if (i < 16 * 128) {
        int c = i >> 7, k = i & 127;
        WatTS[i] = (c < 8) ? f2bf(ldF(Wat, (size_t)k * 8 + c, isb))
                           : f2bf(ldF(Wat, (size_t)(384 + k) * 8 + (c - 8), isb));
    }
}

// ---------------- K1: node pipeline (MFMA): emb -> base, c_ts -----------------------------
// 32 nodes/block, 4 waves: wave -> (m = wid&1 row-half, nh = wid>>1 col-half).
// Stage A: emb[32,128] = select_ty( X[32,256] @ WnT[ty] )    -> LDS (bf16)
// Stage B: base[32,128] = emb @ Wu1                          -> global bf16
// Stage C: c_ts[32,16] = emb @ [Wat_tar|Wat_src]             -> global f32
__global__ __launch_bounds__(256) void k_node(
    const void* __restrict__ nf, const void* __restrict__ ntype,
    const unsigned short* __restrict__ WnT, const unsigned short* __restrict__ Wu1T,
    const unsigned short* __restrict__ WatTS,
    unsigned short* __restrict__ base, float* __restrict__ c_ts,
    const int* __restrict__ flags)
{
    const bool isb = flags[0] != 0, i64 = flags[1] != 0;
    const int t = threadIdx.x, lane = t & 63, wid = t >> 6;
    const int m = wid & 1, nh = wid >> 1;
    const int lr = lane & 15, lg = lane >> 4;
    const int n0 = blockIdx.x * 32;

    // stride 264 (bf16): bank = 4*row + koff/4 pattern -> <=2-way (free)
    __shared__ __align__(16) unsigned short s_x[32 * 264];
    __shared__ __align__(16) unsigned short s_emb[32 * 136];
    __shared__ int s_ty[32];

    if (t < 32) {
        int nn = n0 + t;
        s_ty[t] = clampi(ldI(ntype, nn < N_NODES ? nn : N_NODES - 1, i64), 0, 2);
    }
    if (isb) {
        for (int i = t; i < 32 * 32; i += 256) {
            int r = i >> 5, c8 = (i & 31) * 8;
            bf16x8 v = (bf16x8)(short)0;
            if (n0 + r < N_NODES)
                v = *(const bf16x8*)((const unsigned short*)nf + (size_t)(n0 + r) * 256 + c8);
            *(bf16x8*)&s_x[r * 264 + c8] = v;
        }
    } else {
        for (int i = t; i < 32 * 64; i += 256) {
            int r = i >> 6, c4 = (i & 63) * 4;
            float4 v = make_float4(0.f, 0.f, 0.f, 0.f);
            if (n0 + r < N_NODES)
                v = *(const float4*)((const float*)nf + (size_t)(n0 + r) * 256 + c4);
            unsigned short* d = &s_x[r * 264 + c4];
            d[0] = f2bf(v.x); d[1] = f2bf(v.y); d[2] = f2bf(v.z); d[3] = f2bf(v.w);
        }
    }
    __syncthreads();

    // ---- Stage A: 3-type projection, K=256 ----
    bf16x8 A[8];
    #pragma unroll
    for (int ks = 0; ks < 8; ++ks)
        A[ks] = *(const bf16x8*)&s_x[(m * 16 + lr) * 264 + ks * 32 + lg * 8];

    f32x4 acc0[4], acc1[4], acc2[4];
    #pragma unroll
    for (int ct = 0; ct < 4; ++ct) {
        acc0[ct] = (f32x4)(0.f); acc1[ct] = (f32x4)(0.f); acc2[ct] = (f32x4)(0.f);
    }
    #pragma unroll
    for (int ct = 0; ct < 4; ++ct) {
        const int crow = nh * 64 + ct * 16 + lr;
        #pragma unroll
        for (int ks = 0; ks < 8; ++ks) {
            const int koff = ks * 32 + lg * 8;
            bf16x8 B0 = *(const bf16x8*)(WnT + (size_t)crow * 256 + koff);
            bf16x8 B1 = *(const bf16x8*)(WnT + (size_t)(128 + crow) * 256 + koff);
            bf16x8 B2 = *(const bf16x8*)(WnT + (size_t)(256 + crow) * 256 + koff);
            acc0[ct] = MFMA_BF16(A[ks], B0, acc0[ct], 0, 0, 0);
            acc1[ct] = MFMA_BF16(A[ks], B1, acc1[ct], 0, 0, 0);
            acc2[ct] = MFMA_BF16(A[ks], B2, acc2[ct], 0, 0, 0);
        }
    }
    // C/D layout: col = lane&15, row = (lane>>4)*4 + j
    #pragma unroll
    for (int ct = 0; ct < 4; ++ct) {
        const int col = nh * 64 + ct * 16 + lr;
        #pragma unroll
        for (int j = 0; j < 4; ++j) {
            const int row = m * 16 + lg * 4 + j;
            int ty = s_ty[row];
            float v = (ty == 0) ? acc0[ct][j] : ((ty == 1) ? acc1[ct][j] : acc2[ct][j]);
            s_emb[row * 136 + col] = f2bf(v);
        }
    }
    __syncthreads();

    // ---- Stage B: base = emb @ Wu1, K=128 ----
    bf16x8 A2[4];
    #pragma unroll
    for (int ks = 0; ks < 4; ++ks)
        A2[ks] = *(const bf16x8*)&s_emb[(m * 16 + lr) * 136 + ks * 32 + lg * 8];

    f32x4 accB[4];
    #pragma unroll
    for (int ct = 0; ct < 4; ++ct) accB[ct] = (f32x4)(0.f);
    #pragma unroll
    for (int ct = 0; ct < 4; ++ct) {
        const int crow = nh * 64 + ct * 16 + lr;
        #pragma unroll
        for (int ks = 0; ks < 4; ++ks) {
            bf16x8 B = *(const bf16x8*)(Wu1T + (size_t)crow * 128 + ks * 32 + lg * 8);
            accB[ct] = MFMA_BF16(A2[ks], B, accB[ct], 0, 0, 0);
        }
    }
    #pragma unroll
    for (int ct = 0; ct < 4; ++ct) {
        const int col = nh * 64 + ct * 16 + lr;
        #pragma unroll
        for (int j = 0; j < 4; ++j) {
            const int n = n0 + m * 16 + lg * 4 + j;
            if (n < N_NODES) base[(size_t)n * 128 + col] = f2bf(accB[ct][j]);
        }
    }

    // ---- Stage C: c_ts = emb @ WatTS, K=128, 16 cols (nh==0 waves only) ----
    if (nh == 0) {
        f32x4 aS = (f32x4)(0.f);
        #pragma unroll
        for (int ks = 0; ks < 4; ++ks) {
            bf16x8 B = *(const bf16x8*)(WatTS + (size_t)lr * 128 + ks * 32 + lg * 8);
            aS = MFMA_BF16(A2[ks], B, aS, 0, 0, 0);
        }
        #pragma unroll
        for (int j = 0; j < 4; ++j) {
            const int n = n0 + m * 16 + lg * 4 + j;
            if (n < N_NODES) c_ts[(size_t)n * 16 + lr] = aS[j];
        }
    }
}

// ---------------- K2: per-edge MFMA (no embedding gather) ---------------------------------
// 64 edges/block, 4 waves: wave = row-tile of 16 edges, full 128 cols in 2 half passes.
// Stage 1: ae/te = lrelu(EA/ET[64,64] @ W[64,128])   -> LDS bf16
// Stage 2: ap = ae @ Wu2                              -> global bf16
// Stage 3: scores = lrelu([ae|te] @ WatMid + c_tar[d] + c_src[s]) -> global f32
__global__ __launch_bounds__(256) void k_edge(
    const void* __restrict__ eattr, const void* __restrict__ etype,
    const void* __restrict__ eidx, const float* __restrict__ c_ts,
    const unsigned short* __restrict__ WeaT, const unsigned short* __restrict__ WetT,
    const unsigned short* __restrict__ Wu2T, const unsigned short* __restrict__ WatMidT,
    float* __restrict__ scores, unsigned short* __restrict__ ap,
    const int* __restrict__ flags)
{
    const bool isb = flags[0] != 0, i64 = flags[1] != 0;
    const int t = threadIdx.x, lane = t & 63, m = t >> 6;
    const int lr = lane & 15, lg = lane >> 4;
    const int e0 = blockIdx.x * 64;

    __shared__ int s_idx[128];                          // [0..63]=src, [64..127]=tar
    __shared__ float s_cs[64 * 16];                     // [e][0..7]=c_tar[d], [8..15]=c_src[s]
    __shared__ __align__(16) unsigned short s_ae[64 * 136];
    __shared__ __align__(16) unsigned short s_te[64 * 136];

    if (t < 128) {
        int e = e0 + (t & 63);
        int v = (t < 64) ? ldI(eidx, (size_t)e, i64)
                         : ldI(eidx, (size_t)N_EDGES + e, i64);
        s_idx[t] = clampi(v, 0, N_NODES - 1);
    }
    __syncthreads();
    // gather per-node score contributions (32B rows)
    for (int i = t; i < 1024; i += 256) {
        int e = i >> 4, c = i & 15;
        int node = (c < 8) ? s_idx[64 + e] : s_idx[e];  // tar part | src part
        s_cs[i] = c_ts[(size_t)node * 16 + c];
    }

    // ---- Stage 1 A-frags from global ----
    const int arow = e0 + m * 16 + lr;
    bf16x8 Aea[2], Aet[2];
    #pragma unroll
    for (int ks = 0; ks < 2; ++ks) {
        const int koff = ks * 32 + lg * 8;
        if (isb) {
            Aea[ks] = *(const bf16x8*)((const unsigned short*)eattr + (size_t)arow * 64 + koff);
            Aet[ks] = *(const bf16x8*)((const unsigned short*)etype + (size_t)arow * 64 + koff);
        } else {
            const float* pa = (const float*)eattr + (size_t)arow * 64 + koff;
            const float* pt = (const float*)etype + (size_t)arow * 64 + koff;
            float4 a0 = *(const float4*)pa, a1 = *(const float4*)(pa + 4);
            float4 t0 = *(const float4*)pt, t1 = *(const float4*)(pt + 4);
            bf16x8 va, vt;
            va[0] = (short)f2bf(a0.x); va[1] = (short)f2bf(a0.y);
            va[2] = (short)f2bf(a0.z); va[3] = (short)f2bf(a0.w);
            va[4] = (short)f2bf(a1.x); va[5] = (short)f2bf(a1.y);
            va[6] = (short)f2bf(a1.z); va[7] = (short)f2bf(a1.w);
            vt[0] = (short)f2bf(t0.x); vt[1] = (short)f2bf(t0.y);
            vt[2] = (short)f2bf(t0.z); vt[3] = (short)f2bf(t0.w);
            vt[4] = (short)f2bf(t1.x); vt[5] = (short)f2bf(t1.y);
            vt[6] = (short)f2bf(t1.z); vt[7] = (short)f2bf(t1.w);
            Aea[ks] = va; Aet[ks] = vt;
        }
    }
    // ---- Stage 1: two col-half passes (bounds VGPRs) ----
    #pragma unroll
    for (int half = 0; half < 2; ++half) {
        f32x4 aa[4], ab[4];
        #pragma unroll
        for (int ct = 0; ct < 4; ++ct) { aa[ct] = (f32x4)(0.f); ab[ct] = (f32x4)(0.f); }
        #pragma unroll
        for (int ct = 0; ct < 4; ++ct) {
            const int crow = half * 64 + ct * 16 + lr;
            #pragma unroll
            for (int ks = 0; ks < 2; ++ks) {
                const int koff = ks * 32 + lg * 8;
                bf16x8 Bea = *(const bf16x8*)(WeaT + (size_t)crow * 64 + koff);
                bf16x8 Bet = *(const bf16x8*)(WetT + (size_t)crow * 64 + koff);
                aa[ct] = MFMA_BF16(Aea[ks], Bea, aa[ct], 0, 0, 0);
                ab[ct] = MFMA_BF16(Aet[ks], Bet, ab[ct], 0, 0, 0);
            }
        }
        #pragma unroll
        for (int ct = 0; ct < 4; ++ct) {
            const int col = half * 64 + ct * 16 + lr;
            #pragma unroll
            for (int j = 0; j < 4; ++j) {
                const int row = m * 16 + lg * 4 + j;
                s_ae[row * 136 + col] = f2bf(lrelu(aa[ct][j]));
                s_te[row * 136 + col] = f2bf(lrelu(ab[ct][j]));
            }
        }
    }
    __syncthreads();   // s_cs cross-thread; LDS writes drained

    // ---- Stage 2: ap = ae @ Wu2 ----
    bf16x8 A2[4];
    #pragma unroll
    for (int ks = 0; ks < 4; ++ks)
        A2[ks] = *(const bf16x8*)&s_ae[(m * 16 + lr) * 136 + ks * 32 + lg * 8];
    #pragma unroll
    for (int half = 0; half < 2; ++half) {
        f32x4 a2[4];
        #pragma unroll
        for (int ct = 0; ct < 4; ++ct) a2[ct] = (f32x4)(0.f);
        #pragma unroll
        for (int ct = 0; ct < 4; ++ct) {
            const int crow = half * 64 + ct * 16 + lr;
            #pragma unroll
            for (int ks = 0; ks < 4; ++ks) {
                bf16x8 B = *(const bf16x8*)(Wu2T + (size_t)crow * 128 + ks * 32 + lg * 8);
                a2[ct] = MFMA_BF16(A2[ks], B, a2[ct], 0, 0, 0);
            }
        }
        #pragma unroll
        for (int ct = 0; ct < 4; ++ct) {
            const int col = half * 64 + ct * 16 + lr;
            #pragma unroll
            for (int j = 0; j < 4; ++j) {
                const int e = e0 + m * 16 + lg * 4 + j;
                ap[(size_t)e * 128 + col] = f2bf(a2[ct][j]);
            }
        }
    }

    // ---- Stage 3: scores, K=256 over [ae|te] + gathered node parts ----
    f32x4 aS = (f32x4)(0.f);
    #pragma unroll
    for (int ks = 0; ks < 8; ++ks) {
        const int koff = (ks & 3) * 32 + lg * 8;
        bf16x8 Af = (ks < 4) ? A2[ks]
                  : *(const bf16x8*)&s_te[(m * 16 + lr) * 136 + koff];
        bf16x8 B = *(const bf16x8*)(WatMidT + (size_t)lr * 256 + ks * 32 + lg * 8);
        aS = MFMA_BF16(Af, B, aS, 0, 0, 0);
    }
    if (lr < 8) {
        #pragma unroll
        for (int j = 0; j < 4; ++j) {
            const int row = m * 16 + lg * 4 + j;
            const int e = e0 + row;
            float v = aS[j] + s_cs[row * 16 + lr] + s_cs[row * 16 + 8 + lr];
            scores[(size_t)e * 8 + lr] = lrelu(v);
        }
    }
}

// ---------------- K3: CSR build over src --------------------------------------------------
__global__ void k_hist(const void* __restrict__ eidx, int* __restrict__ counts,
                       const int* __restrict__ flags)
{
    const bool i64 = flags[1] != 0;
    int e = blockIdx.x * blockDim.x + threadIdx.x;
    if (e < N_EDGES) atomicAdd(&counts[clampi(ldI(eidx, e, i64), 0, N_NODES - 1)], 1);
}

__global__ __launch_bounds__(256) void k_scan1(const int* __restrict__ counts,
                                               int* __restrict__ offsets, int* __restrict__ bsum)
{
    __shared__ int buf[256];
    int b = blockIdx.x, t = threadIdx.x, i = b * 256 + t;
    int v = (i < N_NODES) ? counts[i] : 0;
    buf[t] = v;
    __syncthreads();
    for (int d = 1; d < 256; d <<= 1) {
        int add = (t >= d) ? buf[t - d] : 0;
        __syncthreads();
        buf[t] += add;
        __syncthreads();
    }
    if (i < N_NODES) offsets[i] = buf[t] - v;
    if (t == 255) bsum[b] = buf[255];
}
__global__ __launch_bounds__(256) void k_scan2(int* __restrict__ bsum, int nb)
{
    __shared__ int buf[256];
    int t = threadIdx.x;
    int v = (t < nb) ? bsum[t] : 0;
    buf[t] = v;
    __syncthreads();
    for (int d = 1; d < 256; d <<= 1) {
        int add = (t >= d) ? buf[t - d] : 0;
        __syncthreads();
        buf[t] += add;
        __syncthreads();
    }
    if (t < nb) bsum[t] = buf[t] - v;
}
__global__ __launch_bounds__(256) void k_scan3(int* __restrict__ offsets,
                                               const int* __restrict__ bsum)
{
    int i = blockIdx.x * 256 + threadIdx.x;
    if (i < N_NODES) offsets[i] += bsum[i >> 8];
    if (i == 0) offsets[N_NODES] = N_EDGES;
}

__global__ void k_scatter(const void* __restrict__ eidx, const int* __restrict__ offsets,
                          int* __restrict__ fill, int* __restrict__ perm,
                          const int* __restrict__ flags)
{
    const bool i64 = flags[1] != 0;
    int e = blockIdx.x * blockDim.x + threadIdx.x;
    if (e >= N_EDGES) return;
    int s = clampi(ldI(eidx, e, i64), 0, N_NODES - 1);
    int p = atomicAdd(&fill[s], 1);
    perm[offsets[s] + p] = e;
}

// ---------------- K4: segment softmax, attn written IN-PLACE into scores ------------------
__global__ void k_stats(float* __restrict__ scores, const int* __restrict__ offsets,
                        const int* __restrict__ perm)
{
    int tid = blockIdx.x * blockDim.x + threadIdx.x;
    if (tid >= N_NODES * 8) return;
    int n = tid >> 3, h = tid & 7;
    int off = offsets[n], deg = offsets[n + 1] - off;
    if (deg <= 0) return;
    float m = -1e30f;
    for (int j = 0; j < deg; ++j) {
        int e = clampi(perm[off + j], 0, N_EDGES - 1);
        m = fmaxf(m, scores[(size_t)e * 8 + h]);
    }
    float d = 0.f;
    for (int j = 0; j < deg; ++j) {
        int e = clampi(perm[off + j], 0, N_EDGES - 1);
        d += expf(scores[(size_t)e * 8 + h] - m);
    }
    float inv = (d > 0.f) ? 1.f / d : 0.f;
    for (int j = 0; j < deg; ++j) {
        int e = clampi(perm[off + j], 0, N_EDGES - 1);
        scores[(size_t)e * 8 + h] = expf(scores[(size_t)e * 8 + h] - m) * inv;
    }
}

// ---------------- K5: lean per-node aggregation -------------------------------------------
// out[n,h,:] = sum_e attn[e,h] * lrelu(base[n] + ap[e])
__global__ __launch_bounds__(128) void k_aggr2(
    const unsigned short* __restrict__ base, const float* __restrict__ attn,
    const unsigned short* __restrict__ ap, const int* __restrict__ offsets,
    const int* __restrict__ perm, void* __restrict__ out, const int* __restrict__ flags)
{
    const bool isb = flags[0] != 0;
    int n = blockIdx.x, t = threadIdx.x;
    float basev = u2f(base[(size_t)n * 128 + t]);
    float acc[8];
    #pragma unroll
    for (int h = 0; h < 8; ++h) acc[h] = 0.f;
    int off = offsets[n], deg = offsets[n + 1] - off;
    for (int j = 0; j < deg; ++j) {
        int e = clampi(perm[off + j], 0, N_EDGES - 1);
        float msg = lrelu(basev + u2f(ap[(size_t)e * 128 + t]));
        const float* at = attn + (size_t)e * 8;   // 32B, broadcast across lanes
        #pragma unroll
        for (int h = 0; h < 8; ++h) acc[h] += at[h] * msg;
    }
    if (isb) {
        __hip_bfloat16* o = (__hip_bfloat16*)out;
        #pragma unroll
        for (int h = 0; h < 8; ++h)
            o[(size_t)n * 1024 + h * 128 + t] = __float2bfloat16(acc[h]);
    } else {
        float* o = (float*)out;
        #pragma unroll
        for (int h = 0; h < 8; ++h)
            o[(size_t)n * 1024 + h * 128 + t] = acc[h];
    }
}

// ---------------- launcher ----------------------------------------------------------------
static inline size_t alignup(size_t x, size_t a) { return (x + a - 1) & ~(a - 1); }

extern "C" void kernel_launch(void* const* d_in, const int* in_sizes, int n_in,
                              void* d_out, int out_size, void* d_ws, size_t ws_size,
                              hipStream_t stream)
{
    const void* nf   = d_in[0];
    const void* eidx = d_in[1];
    const void* eatt = d_in[2];
    const void* etyp = d_in[3];
    const void* ntyp = d_in[4];
    // d_in[5] edge_type_list: unused by the reference
    const void* Wn   = d_in[6];
    const void* Wea  = d_in[7];
    const void* Wet  = d_in[8];
    const void* Wup  = d_in[9];
    const void* Wat  = d_in[10];

    // workspace layout (~133.5 MB — same footprint as previously-verified round)
    char* w = (char*)d_ws;
    size_t off = 16;
    int* flags = (int*)w;
    unsigned short* base = (unsigned short*)(w + off);  off += (size_t)N_NODES * 128 * 2;
    float* c_ts   = (float*)(w + off);                  off += (size_t)N_NODES * 16 * 4;
    float* scores = (float*)(w + off);                  off += (size_t)N_EDGES * 8 * 4;
    int* counts   = (int*)(w + off);                    off += (size_t)N_NODES * 4;
    int* offsets  = (int*)(w + off);                    off += (size_t)(N_NODES + 1) * 4;
    int* perm     = (int*)(w + off);                    off += (size_t)N_EDGES * 4;
    int* bsum     = (int*)(w + off);                    off += 1024;
    off = alignup(off, 16);
    unsigned short* WnT     = (unsigned short*)(w + off); off += (size_t)3 * 128 * 256 * 2;
    unsigned short* WeaT    = (unsigned short*)(w + off); off += 128 * 64 * 2;
    unsigned short* WetT    = (unsigned short*)(w + off); off += 128 * 64 * 2;
    unsigned short* Wu1T    = (unsigned short*)(w + off); off += 128 * 128 * 2;
    unsigned short* Wu2T    = (unsigned short*)(w + off); off += 128 * 128 * 2;
    unsigned short* WatMidT = (unsigned short*)(w + off); off += 16 * 256 * 2;
    unsigned short* WatTS   = (unsigned short*)(w + off); off += 16 * 128 * 2;
    off = alignup(off, 16);
    unsigned short* ap = (unsigned short*)(w + off);

    hipMemsetAsync(counts, 0, N_NODES * sizeof(int), stream);

    k_detect<<<1, 64, 0, stream>>>(nf, eidx, flags);
    k_wprep<<<384, 256, 0, stream>>>(Wn, Wea, Wet, Wup, Wat,
                                     WnT, WeaT, WetT, Wu1T, Wu2T, WatMidT, WatTS, flags);
    k_node<<<(N_NODES + 31) / 32, 256, 0, stream>>>(nf, ntyp, WnT, Wu1T, WatTS,
                                                    base, c_ts, flags);
    k_edge<<<N_EDGES / 64, 256, 0, stream>>>(eatt, etyp, eidx, c_ts,
                                             WeaT, WetT, Wu2T, WatMidT, scores, ap, flags);
    k_hist<<<(N_EDGES + 255) / 256, 256, 0, stream>>>(eidx, counts, flags);
    const int SB = (N_NODES + 255) / 256;
    k_scan1<<<SB, 256, 0, stream>>>(counts, offsets, bsum);
    k_scan2<<<1, 256, 0, stream>>>(bsum, SB);
    k_scan3<<<SB, 256, 0, stream>>>(offsets, bsum);
    hipMemsetAsync(counts, 0, N_NODES * sizeof(int), stream);   // reuse counts as fill
    k_scatter<<<(N_EDGES + 255) / 256, 256, 0, stream>>>(eidx, offsets, counts, perm, flags);
    k_stats<<<(N_NODES * 8 + 255) / 256, 256, 0, stream>>>(scores, offsets, perm);
    k_aggr2<<<N_NODES, 128, 0, stream>>>(base, scores, ap, offsets, perm, d_out, flags);
}

// Round 3
// 828.978 us; speedup vs baseline: 4.5400x; 1.0902x over previous
//
#include <hip/hip_runtime.h>
#include <hip/hip_bf16.h>

#define N_NODES 50000
#define N_EDGES 400000
#define SLOPE 0.2f

typedef __attribute__((ext_vector_type(8))) short bf16x8;   // 8 bf16 = 4 VGPR (MFMA A/B frag)
typedef __attribute__((ext_vector_type(4))) float f32x4;    // MFMA C/D frag
#define MFMA_BF16 __builtin_amdgcn_mfma_f32_16x16x32_bf16

static __device__ __forceinline__ float lrelu(float x) { return x >= 0.f ? x : SLOPE * x; }
static __device__ __forceinline__ float b2f(__hip_bfloat16 x) { return __bfloat162float(x); }
static __device__ __forceinline__ float u2f(unsigned short u) {
    union { unsigned short u; __hip_bfloat16 b; } cv; cv.u = u; return __bfloat162float(cv.b);
}
static __device__ __forceinline__ unsigned short f2bf(float x) {
    union { __hip_bfloat16 b; unsigned short u; } cv; cv.b = __float2bfloat16(x); return cv.u;
}
static __device__ __forceinline__ int clampi(int v, int lo, int hi) {
    return v < lo ? lo : (v > hi ? hi : v);
}
// dual-dtype float load: isb ? bf16 : f32
static __device__ __forceinline__ float ldF(const void* __restrict__ p, size_t i, bool isb) {
    return isb ? b2f(((const __hip_bfloat16*)p)[i]) : ((const float*)p)[i];
}
// dual-width index load: i64 ? int64 : int32
static __device__ __forceinline__ int ldI(const void* __restrict__ p, size_t i, bool i64) {
    return i64 ? (int)(((const long long*)p)[i]) : ((const int*)p)[i];
}

// ---------------- K0: dtype detection ----------------------------------------------------
__global__ void k_detect(const void* __restrict__ nf, const void* __restrict__ eidx,
                         int* __restrict__ flags)
{
    int t = threadIdx.x;  // 64 threads
    float x = b2f(((const __hip_bfloat16*)nf)[2 * t]);
    bool bad = !(x == x) || fabsf(x) > 1e4f;
    unsigned long long fmask = __ballot(bad);
    int v = ((const int*)eidx)[2 * t + 1];
    unsigned long long imask = __ballot(v != 0);
    if (t == 0) {
        flags[0] = (fmask == 0ull) ? 1 : 0;  // 1 => floats are bf16
        flags[1] = (imask == 0ull) ? 1 : 0;  // 1 => ints are int64
    }
}

// ---------------- K0b: weight prep (transpose + bf16-ify) --------------------------------
// All *T layouts are [out_col][k] bf16 so B-fragments are contiguous 16B loads with the
// same k-mapping as A-fragments (k-permutation-robust).
__global__ __launch_bounds__(256) void k_wprep(
    const void* __restrict__ Wn, const void* __restrict__ Wea, const void* __restrict__ Wet,
    const void* __restrict__ Wup, const void* __restrict__ Wat,
    unsigned short* __restrict__ WnT, unsigned short* __restrict__ WeaT,
    unsigned short* __restrict__ WetT, unsigned short* __restrict__ Wu1T,
    unsigned short* __restrict__ Wu2T, unsigned short* __restrict__ WatMidT,
    unsigned short* __restrict__ WatTS, const int* __restrict__ flags)
{
    const bool isb = flags[0] != 0;
    int i = blockIdx.x * 256 + threadIdx.x;
    if (i < 3 * 128 * 256) {
        int ty = i >> 15, rem = i & 32767, c = rem >> 8, k = rem & 255;
        WnT[i] = f2bf(ldF(Wn, ((size_t)ty * 256 + k) * 128 + c, isb));
    }
    if (i < 128 * 128) {
        int c = i >> 7, k = i & 127;
        Wu1T[i] = f2bf(ldF(Wup, (size_t)k * 128 + c, isb));
        Wu2T[i] = f2bf(ldF(Wup, (size_t)(128 + k) * 128 + c, isb));
    }
    if (i < 128 * 64) {
        int c = i >> 6, k = i & 63;
        WeaT[i] = f2bf(ldF(Wea, (size_t)k * 128 + c, isb));
        WetT[i] = f2bf(ldF(Wet, (size_t)k * 128 + c, isb));
    }
    if (i < 16 * 256) {
        int c = i >> 8, k = i & 255;
        WatMidT[i] = (c < 8) ? f2bf(ldF(Wat, (size_t)(128 + k) * 8 + c, isb)) : (unsigned short)0;
    }
    if (i < 16 * 128) {
        int c = i >> 7, k = i & 127;
        WatTS[i] = (c < 8) ? f2bf(ldF(Wat, (size_t)k * 8 + c, isb))
                           : f2bf(ldF(Wat, (size_t)(384 + k) * 8 + (c - 8), isb));
    }
}

// ---------------- K1: node pipeline (MFMA): emb -> base, c_ts -----------------------------
__global__ __launch_bounds__(256) void k_node(
    const void* __restrict__ nf, const void* __restrict__ ntype,
    const unsigned short* __restrict__ WnT, const unsigned short* __restrict__ Wu1T,
    const unsigned short* __restrict__ WatTS,
    unsigned short* __restrict__ base, float* __restrict__ c_ts,
    const int* __restrict__ flags)
{
    const bool isb = flags[0] != 0, i64 = flags[1] != 0;
    const int t = threadIdx.x, lane = t & 63, wid = t >> 6;
    const int m = wid & 1, nh = wid >> 1;
    const int lr = lane & 15, lg = lane >> 4;
    const int n0 = blockIdx.x * 32;

    __shared__ __align__(16) unsigned short s_x[32 * 264];
    __shared__ __align__(16) unsigned short s_emb[32 * 136];
    __shared__ int s_ty[32];

    if (t < 32) {
        int nn = n0 + t;
        s_ty[t] = clampi(ldI(ntype, nn < N_NODES ? nn : N_NODES - 1, i64), 0, 2);
    }
    if (isb) {
        for (int i = t; i < 32 * 32; i += 256) {
            int r = i >> 5, c8 = (i & 31) * 8;
            bf16x8 v = (bf16x8)(short)0;
            if (n0 + r < N_NODES)
                v = *(const bf16x8*)((const unsigned short*)nf + (size_t)(n0 + r) * 256 + c8);
            *(bf16x8*)&s_x[r * 264 + c8] = v;
        }
    } else {
        for (int i = t; i < 32 * 64; i += 256) {
            int r = i >> 6, c4 = (i & 63) * 4;
            float4 v = make_float4(0.f, 0.f, 0.f, 0.f);
            if (n0 + r < N_NODES)
                v = *(const float4*)((const float*)nf + (size_t)(n0 + r) * 256 + c4);
            unsigned short* d = &s_x[r * 264 + c4];
            d[0] = f2bf(v.x); d[1] = f2bf(v.y); d[2] = f2bf(v.z); d[3] = f2bf(v.w);
        }
    }
    __syncthreads();

    // ---- Stage A: 3-type projection, K=256 ----
    bf16x8 A[8];
    #pragma unroll
    for (int ks = 0; ks < 8; ++ks)
        A[ks] = *(const bf16x8*)&s_x[(m * 16 + lr) * 264 + ks * 32 + lg * 8];

    f32x4 acc0[4], acc1[4], acc2[4];
    #pragma unroll
    for (int ct = 0; ct < 4; ++ct) {
        acc0[ct] = (f32x4)(0.f); acc1[ct] = (f32x4)(0.f); acc2[ct] = (f32x4)(0.f);
    }
    #pragma unroll
    for (int ct = 0; ct < 4; ++ct) {
        const int crow = nh * 64 + ct * 16 + lr;
        #pragma unroll
        for (int ks = 0; ks < 8; ++ks) {
            const int koff = ks * 32 + lg * 8;
            bf16x8 B0 = *(const bf16x8*)(WnT + (size_t)crow * 256 + koff);
            bf16x8 B1 = *(const bf16x8*)(WnT + (size_t)(128 + crow) * 256 + koff);
            bf16x8 B2 = *(const bf16x8*)(WnT + (size_t)(256 + crow) * 256 + koff);
            acc0[ct] = MFMA_BF16(A[ks], B0, acc0[ct], 0, 0, 0);
            acc1[ct] = MFMA_BF16(A[ks], B1, acc1[ct], 0, 0, 0);
            acc2[ct] = MFMA_BF16(A[ks], B2, acc2[ct], 0, 0, 0);
        }
    }
    #pragma unroll
    for (int ct = 0; ct < 4; ++ct) {
        const int col = nh * 64 + ct * 16 + lr;
        #pragma unroll
        for (int j = 0; j < 4; ++j) {
            const int row = m * 16 + lg * 4 + j;
            int ty = s_ty[row];
            float v = (ty == 0) ? acc0[ct][j] : ((ty == 1) ? acc1[ct][j] : acc2[ct][j]);
            s_emb[row * 136 + col] = f2bf(v);
        }
    }
    __syncthreads();

    // ---- Stage B: base = emb @ Wu1, K=128 ----
    bf16x8 A2[4];
    #pragma unroll
    for (int ks = 0; ks < 4; ++ks)
        A2[ks] = *(const bf16x8*)&s_emb[(m * 16 + lr) * 136 + ks * 32 + lg * 8];

    f32x4 accB[4];
    #pragma unroll
    for (int ct = 0; ct < 4; ++ct) accB[ct] = (f32x4)(0.f);
    #pragma unroll
    for (int ct = 0; ct < 4; ++ct) {
        const int crow = nh * 64 + ct * 16 + lr;
        #pragma unroll
        for (int ks = 0; ks < 4; ++ks) {
            bf16x8 B = *(const bf16x8*)(Wu1T + (size_t)crow * 128 + ks * 32 + lg * 8);
            accB[ct] = MFMA_BF16(A2[ks], B, accB[ct], 0, 0, 0);
        }
    }
    #pragma unroll
    for (int ct = 0; ct < 4; ++ct) {
        const int col = nh * 64 + ct * 16 + lr;
        #pragma unroll
        for (int j = 0; j < 4; ++j) {
            const int n = n0 + m * 16 + lg * 4 + j;
            if (n < N_NODES) base[(size_t)n * 128 + col] = f2bf(accB[ct][j]);
        }
    }

    // ---- Stage C: c_ts = emb @ WatTS (nh==0 waves) ----
    if (nh == 0) {
        f32x4 aS = (f32x4)(0.f);
        #pragma unroll
        for (int ks = 0; ks < 4; ++ks) {
            bf16x8 B = *(const bf16x8*)(WatTS + (size_t)lr * 128 + ks * 32 + lg * 8);
            aS = MFMA_BF16(A2[ks], B, aS, 0, 0, 0);
        }
        #pragma unroll
        for (int j = 0; j < 4; ++j) {
            const int n = n0 + m * 16 + lg * 4 + j;
            if (n < N_NODES) c_ts[(size_t)n * 16 + lr] = aS[j];
        }
    }
}

// ---------------- K2 helpers --------------------------------------------------------------
static __device__ __forceinline__ void load_afrag64(
    bf16x8 Af[2], const void* __restrict__ src, int arow, int lg, bool isb)
{
    #pragma unroll
    for (int ks = 0; ks < 2; ++ks) {
        const int koff = ks * 32 + lg * 8;
        if (isb) {
            Af[ks] = *(const bf16x8*)((const unsigned short*)src + (size_t)arow * 64 + koff);
        } else {
            const float* p = (const float*)src + (size_t)arow * 64 + koff;
            float4 a0 = *(const float4*)p, a1 = *(const float4*)(p + 4);
            bf16x8 v;
            v[0] = (short)f2bf(a0.x); v[1] = (short)f2bf(a0.y);
            v[2] = (short)f2bf(a0.z); v[3] = (short)f2bf(a0.w);
            v[4] = (short)f2bf(a1.x); v[5] = (short)f2bf(a1.y);
            v[6] = (short)f2bf(a1.z); v[7] = (short)f2bf(a1.w);
            Af[ks] = v;
        }
    }
}

// project [16 edges x 64] @ WT[128][64] -> lrelu -> s_buf rows (wave-private 16-row region)
static __device__ __forceinline__ void proj64_to_lds(
    const bf16x8 Af[2], const unsigned short* __restrict__ WT,
    unsigned short* __restrict__ s_buf, int m, int lr, int lg)
{
    #pragma unroll
    for (int half = 0; half < 2; ++half) {
        f32x4 acc[4];
        #pragma unroll
        for (int ct = 0; ct < 4; ++ct) acc[ct] = (f32x4)(0.f);
        #pragma unroll
        for (int ct = 0; ct < 4; ++ct) {
            const int crow = half * 64 + ct * 16 + lr;
            #pragma unroll
            for (int ks = 0; ks < 2; ++ks) {
                bf16x8 B = *(const bf16x8*)(WT + (size_t)crow * 64 + ks * 32 + lg * 8);
                acc[ct] = MFMA_BF16(Af[ks], B, acc[ct], 0, 0, 0);
            }
        }
        #pragma unroll
        for (int ct = 0; ct < 4; ++ct) {
            const int col = half * 64 + ct * 16 + lr;
            #pragma unroll
            for (int j = 0; j < 4; ++j)
                s_buf[(m * 16 + lg * 4 + j) * 132 + col] = f2bf(lrelu(acc[ct][j]));
        }
    }
}

// ---------------- K2: per-edge MFMA, CSR-slot output --------------------------------------
// 32 edges/block, 128 threads = 2 waves; wave m owns edge rows [m*16, m*16+16).
// ONE shared buffer, used sequentially (all buf accesses wave-private between barriers):
//   te -> s_buf -> score-partial;  ae -> s_buf -> score-partial + ap;  ap -> s_buf -> store
// scores/ap written at CSR slot inv[e] so downstream reads are sequential.
__global__ __launch_bounds__(128) void k_edge(
    const void* __restrict__ eattr, const void* __restrict__ etype,
    const void* __restrict__ eidx, const float* __restrict__ c_ts,
    const unsigned short* __restrict__ WeaT, const unsigned short* __restrict__ WetT,
    const unsigned short* __restrict__ Wu2T, const unsigned short* __restrict__ WatMidT,
    const int* __restrict__ inv, float* __restrict__ scores,
    unsigned short* __restrict__ ap, const int* __restrict__ flags)
{
    const bool isb = flags[0] != 0, i64 = flags[1] != 0;
    const int t = threadIdx.x, lane = t & 63, m = t >> 6;   // m in {0,1}
    const int lr = lane & 15, lg = lane >> 4;
    const int e0 = blockIdx.x * 32;

    __shared__ int s_idx[64];                            // [0..31]=src, [32..63]=tar
    __shared__ int s_slot[32];
    __shared__ float s_cs[32 * 16];                      // [e][0..7]=c_tar, [8..15]=c_src
    __shared__ __align__(16) unsigned short s_buf[32 * 132];

    if (t < 64) {
        int e = e0 + (t & 31);
        int v = (t < 32) ? ldI(eidx, (size_t)e, i64)
                         : ldI(eidx, (size_t)N_EDGES + e, i64);
        s_idx[t] = clampi(v, 0, N_NODES - 1);
    }
    if (t < 32) s_slot[t] = clampi(inv[e0 + t], 0, N_EDGES - 1);
    __syncthreads();                                     // b1: s_idx/s_slot visible

    for (int i = t; i < 512; i += 128) {                 // c_ts gather (32B rows)
        int e = i >> 4, c = i & 15;
        int node = (c < 8) ? s_idx[32 + e] : s_idx[e];
        s_cs[i] = c_ts[(size_t)node * 16 + c];
    }

    const int arow = e0 + m * 16 + lr;
    f32x4 aS = (f32x4)(0.f);

    // ---- phase A: te = lrelu(ET @ Wet) -> s_buf (own rows) ----
    {
        bf16x8 Aet[2];
        load_afrag64(Aet, etype, arow, lg, isb);
        proj64_to_lds(Aet, WetT, s_buf, m, lr, lg);
    }
    // ---- phase B: score partial from te (reads own rows; wave-private, no barrier) ----
    #pragma unroll
    for (int ks = 0; ks < 4; ++ks) {
        bf16x8 A = *(const bf16x8*)&s_buf[(m * 16 + lr) * 132 + ks * 32 + lg * 8];
        bf16x8 B = *(const bf16x8*)(WatMidT + (size_t)lr * 256 + 128 + ks * 32 + lg * 8);
        aS = MFMA_BF16(A, B, aS, 0, 0, 0);
    }
    // ---- phase C: ae = lrelu(EA @ Wea) -> s_buf (own rows; own reads completed above) ----
    {
        bf16x8 Aea[2];
        load_afrag64(Aea, eattr, arow, lg, isb);
        proj64_to_lds(Aea, WeaT, s_buf, m, lr, lg);
    }
    // ---- phase D: A2 from own rows; score partial from ae ----
    bf16x8 A2[4];
    #pragma unroll
    for (int ks = 0; ks < 4; ++ks)
        A2[ks] = *(const bf16x8*)&s_buf[(m * 16 + lr) * 132 + ks * 32 + lg * 8];
    #pragma unroll
    for (int ks = 0; ks < 4; ++ks) {
        bf16x8 B = *(const bf16x8*)(WatMidT + (size_t)lr * 256 + ks * 32 + lg * 8);
        aS = MFMA_BF16(A2[ks], B, aS, 0, 0, 0);
    }
    __syncthreads();                                     // b2: s_cs ready (all threads)

    if (lr < 8) {
        #pragma unroll
        for (int j = 0; j < 4; ++j) {
            const int row = m * 16 + lg * 4 + j;
            float v = aS[j] + s_cs[row * 16 + lr] + s_cs[row * 16 + 8 + lr];
            scores[(size_t)s_slot[row] * 8 + lr] = lrelu(v);
        }
    }

    // ---- stage 2: ap = ae @ Wu2 -> s_buf (A2 in regs; own-row writes) ----
    #pragma unroll
    for (int half = 0; half < 2; ++half) {
        f32x4 a2[4];
        #pragma unroll
        for (int ct = 0; ct < 4; ++ct) a2[ct] = (f32x4)(0.f);
        #pragma unroll
        for (int ct = 0; ct < 4; ++ct) {
            const int crow = half * 64 + ct * 16 + lr;
            #pragma unroll
            for (int ks = 0; ks < 4; ++ks) {
                bf16x8 B = *(const bf16x8*)(Wu2T + (size_t)crow * 128 + ks * 32 + lg * 8);
                a2[ct] = MFMA_BF16(A2[ks], B, a2[ct], 0, 0, 0);
            }
        }
        #pragma unroll
        for (int ct = 0; ct < 4; ++ct) {
            const int col = half * 64 + ct * 16 + lr;
            #pragma unroll
            for (int j = 0; j < 4; ++j)
                s_buf[(m * 16 + lg * 4 + j) * 132 + col] = f2bf(a2[ct][j]);
        }
    }
    __syncthreads();                                     // b3: all ap rows in LDS

    // coalesced ap store: row r -> slot, 16 lanes x 16B = 256B per row
    #pragma unroll
    for (int i = 0; i < 4; ++i) {
        int r = (t >> 4) + i * 8;
        int c8 = (t & 15) * 8;
        bf16x8 v = *(const bf16x8*)&s_buf[r * 132 + c8];
        *(bf16x8*)(ap + (size_t)s_slot[r] * 128 + c8) = v;
    }
}

// ---------------- K3: CSR build over src --------------------------------------------------
__global__ void k_hist(const void* __restrict__ eidx, int* __restrict__ counts,
                       const int* __restrict__ flags)
{
    const bool i64 = flags[1] != 0;
    int e = blockIdx.x * blockDim.x + threadIdx.x;
    if (e < N_EDGES) atomicAdd(&counts[clampi(ldI(eidx, e, i64), 0, N_NODES - 1)], 1);
}

__global__ __launch_bounds__(256) void k_scan1(const int* __restrict__ counts,
                                               int* __restrict__ offsets, int* __restrict__ bsum)
{
    __shared__ int buf[256];
    int b = blockIdx.x, t = threadIdx.x, i = b * 256 + t;
    int v = (i < N_NODES) ? counts[i] : 0;
    buf[t] = v;
    __syncthreads();
    for (int d = 1; d < 256; d <<= 1) {
        int add = (t >= d) ? buf[t - d] : 0;
        __syncthreads();
        buf[t] += add;
        __syncthreads();
    }
    if (i < N_NODES) offsets[i] = buf[t] - v;
    if (t == 255) bsum[b] = buf[255];
}
__global__ __launch_bounds__(256) void k_scan2(int* __restrict__ bsum, int nb)
{
    __shared__ int buf[256];
    int t = threadIdx.x;
    int v = (t < nb) ? bsum[t] : 0;
    buf[t] = v;
    __syncthreads();
    for (int d = 1; d < 256; d <<= 1) {
        int add = (t >= d) ? buf[t - d] : 0;
        __syncthreads();
        buf[t] += add;
        __syncthreads();
    }
    if (t < nb) bsum[t] = buf[t] - v;
}
__global__ __launch_bounds__(256) void k_scan3(int* __restrict__ offsets,
                                               const int* __restrict__ bsum)
{
    int i = blockIdx.x * 256 + threadIdx.x;
    if (i < N_NODES) offsets[i] += bsum[i >> 8];
    if (i == 0) offsets[N_NODES] = N_EDGES;
}

// writes INVERSE permutation: inv[e] = CSR slot of edge e
__global__ void k_scatter(const void* __restrict__ eidx, const int* __restrict__ offsets,
                          int* __restrict__ fill, int* __restrict__ inv,
                          const int* __restrict__ flags)
{
    const bool i64 = flags[1] != 0;
    int e = blockIdx.x * blockDim.x + threadIdx.x;
    if (e >= N_EDGES) return;
    int s = clampi(ldI(eidx, e, i64), 0, N_NODES - 1);
    int p = atomicAdd(&fill[s], 1);
    inv[e] = offsets[s] + p;
}

// ---------------- K4: segment softmax in slot order (sequential reads) --------------------
__global__ void k_stats(float* __restrict__ scores, const int* __restrict__ offsets)
{
    int tid = blockIdx.x * blockDim.x + threadIdx.x;
    if (tid >= N_NODES * 8) return;
    int n = tid >> 3, h = tid & 7;
    int off = offsets[n], deg = offsets[n + 1] - off;
    if (deg <= 0) return;
    float m = -1e30f;
    for (int j = 0; j < deg; ++j)
        m = fmaxf(m, scores[(size_t)(off + j) * 8 + h]);
    float d = 0.f;
    for (int j = 0; j < deg; ++j)
        d += expf(scores[(size_t)(off + j) * 8 + h] - m);
    float inv = (d > 0.f) ? 1.f / d : 0.f;
    for (int j = 0; j < deg; ++j) {
        size_t idx = (size_t)(off + j) * 8 + h;
        scores[idx] = expf(scores[idx] - m) * inv;
    }
}

// ---------------- K5: lean per-node aggregation (fully streaming reads) -------------------
__global__ __launch_bounds__(128) void k_aggr2(
    const unsigned short* __restrict__ base, const float* __restrict__ attn,
    const unsigned short* __restrict__ ap, const int* __restrict__ offsets,
    void* __restrict__ out, const int* __restrict__ flags)
{
    const bool isb = flags[0] != 0;
    int n = blockIdx.x, t = threadIdx.x;
    float basev = u2f(base[(size_t)n * 128 + t]);
    float acc[8];
    #pragma unroll
    for (int h = 0; h < 8; ++h) acc[h] = 0.f;
    int off = offsets[n], deg = offsets[n + 1] - off;
    for (int j = 0; j < deg; ++j) {
        size_t slot = (size_t)(off + j);
        float msg = lrelu(basev + u2f(ap[slot * 128 + t]));
        const float* at = attn + slot * 8;     // 32B, broadcast across lanes
        #pragma unroll
        for (int h = 0; h < 8; ++h) acc[h] += at[h] * msg;
    }
    if (isb) {
        __hip_bfloat16* o = (__hip_bfloat16*)out;
        #pragma unroll
        for (int h = 0; h < 8; ++h)
            o[(size_t)n * 1024 + h * 128 + t] = __float2bfloat16(acc[h]);
    } else {
        float* o = (float*)out;
        #pragma unroll
        for (int h = 0; h < 8; ++h)
            o[(size_t)n * 1024 + h * 128 + t] = acc[h];
    }
}

// ---------------- launcher ----------------------------------------------------------------
static inline size_t alignup(size_t x, size_t a) { return (x + a - 1) & ~(a - 1); }

extern "C" void kernel_launch(void* const* d_in, const int* in_sizes, int n_in,
                              void* d_out, int out_size, void* d_ws, size_t ws_size,
                              hipStream_t stream)
{
    const void* nf   = d_in[0];
    const void* eidx = d_in[1];
    const void* eatt = d_in[2];
    const void* etyp = d_in[3];
    const void* ntyp = d_in[4];
    // d_in[5] edge_type_list: unused by the reference
    const void* Wn   = d_in[6];
    const void* Wea  = d_in[7];
    const void* Wet  = d_in[8];
    const void* Wup  = d_in[9];
    const void* Wat  = d_in[10];

    // workspace layout (~133.5 MB, same footprint as verified rounds)
    char* w = (char*)d_ws;
    size_t off = 16;
    int* flags = (int*)w;
    unsigned short* base = (unsigned short*)(w + off);  off += (size_t)N_NODES * 128 * 2;
    float* c_ts   = (float*)(w + off);                  off += (size_t)N_NODES * 16 * 4;
    float* scores = (float*)(w + off);                  off += (size_t)N_EDGES * 8 * 4;
    int* counts   = (int*)(w + off);                    off += (size_t)N_NODES * 4;
    int* offsets  = (int*)(w + off);                    off += (size_t)(N_NODES + 1) * 4;
    int* inv      = (int*)(w + off);                    off += (size_t)N_EDGES * 4;
    int* bsum     = (int*)(w + off);                    off += 1024;
    off = alignup(off, 16);
    unsigned short* WnT     = (unsigned short*)(w + off); off += (size_t)3 * 128 * 256 * 2;
    unsigned short* WeaT    = (unsigned short*)(w + off); off += 128 * 64 * 2;
    unsigned short* WetT    = (unsigned short*)(w + off); off += 128 * 64 * 2;
    unsigned short* Wu1T    = (unsigned short*)(w + off); off += 128 * 128 * 2;
    unsigned short* Wu2T    = (unsigned short*)(w + off); off += 128 * 128 * 2;
    unsigned short* WatMidT = (unsigned short*)(w + off); off += 16 * 256 * 2;
    unsigned short* WatTS   = (unsigned short*)(w + off); off += 16 * 128 * 2;
    off = alignup(off, 16);
    unsigned short* ap = (unsigned short*)(w + off);

    hipMemsetAsync(counts, 0, N_NODES * sizeof(int), stream);

    k_detect<<<1, 64, 0, stream>>>(nf, eidx, flags);
    k_wprep<<<384, 256, 0, stream>>>(Wn, Wea, Wet, Wup, Wat,
                                     WnT, WeaT, WetT, Wu1T, Wu2T, WatMidT, WatTS, flags);
    // CSR first (so k_edge can scatter outputs to slots)
    k_hist<<<(N_EDGES + 255) / 256, 256, 0, stream>>>(eidx, counts, flags);
    const int SB = (N_NODES + 255) / 256;
    k_scan1<<<SB, 256, 0, stream>>>(counts, offsets, bsum);
    k_scan2<<<1, 256, 0, stream>>>(bsum, SB);
    k_scan3<<<SB, 256, 0, stream>>>(offsets, bsum);
    hipMemsetAsync(counts, 0, N_NODES * sizeof(int), stream);   // reuse counts as fill
    k_scatter<<<(N_EDGES + 255) / 256, 256, 0, stream>>>(eidx, offsets, counts, inv, flags);

    k_node<<<(N_NODES + 31) / 32, 256, 0, stream>>>(nf, ntyp, WnT, Wu1T, WatTS,
                                                    base, c_ts, flags);
    k_edge<<<N_EDGES / 32, 128, 0, stream>>>(eatt, etyp, eidx, c_ts,
                                             WeaT, WetT, Wu2T, WatMidT,
                                             inv, scores, ap, flags);
    k_stats<<<(N_NODES * 8 + 255) / 256, 256, 0, stream>>>(scores, offsets);
    k_aggr2<<<N_NODES, 128, 0, stream>>>(base, scores, ap, offsets, d_out, flags);
}

// Round 4
// 812.715 us; speedup vs baseline: 4.6308x; 1.0200x over previous
//
#include <hip/hip_runtime.h>
#include <hip/hip_bf16.h>

#define N_NODES 50000
#define N_EDGES 400000
#define SLOPE 0.2f

typedef __attribute__((ext_vector_type(8))) short bf16x8;   // 8 bf16 = 4 VGPR (MFMA A/B frag)
typedef __attribute__((ext_vector_type(4))) float f32x4;    // MFMA C/D frag
#define MFMA_BF16 __builtin_amdgcn_mfma_f32_16x16x32_bf16

static __device__ __forceinline__ float lrelu(float x) { return x >= 0.f ? x : SLOPE * x; }
static __device__ __forceinline__ float b2f(__hip_bfloat16 x) { return __bfloat162float(x); }
static __device__ __forceinline__ float u2f(unsigned short u) {
    union { unsigned short u; __hip_bfloat16 b; } cv; cv.u = u; return __bfloat162float(cv.b);
}
static __device__ __forceinline__ unsigned short f2bf(float x) {
    union { __hip_bfloat16 b; unsigned short u; } cv; cv.b = __float2bfloat16(x); return cv.u;
}
static __device__ __forceinline__ int clampi(int v, int lo, int hi) {
    return v < lo ? lo : (v > hi ? hi : v);
}
// dual-dtype float load: isb ? bf16 : f32
static __device__ __forceinline__ float ldF(const void* __restrict__ p, size_t i, bool isb) {
    return isb ? b2f(((const __hip_bfloat16*)p)[i]) : ((const float*)p)[i];
}
// dual-width index load: i64 ? int64 : int32
static __device__ __forceinline__ int ldI(const void* __restrict__ p, size_t i, bool i64) {
    return i64 ? (int)(((const long long*)p)[i]) : ((const int*)p)[i];
}

// ---------------- K0: dtype detection ----------------------------------------------------
__global__ void k_detect(const void* __restrict__ nf, const void* __restrict__ eidx,
                         int* __restrict__ flags)
{
    int t = threadIdx.x;  // 64 threads
    float x = b2f(((const __hip_bfloat16*)nf)[2 * t]);
    bool bad = !(x == x) || fabsf(x) > 1e4f;
    unsigned long long fmask = __ballot(bad);
    int v = ((const int*)eidx)[2 * t + 1];
    unsigned long long imask = __ballot(v != 0);
    if (t == 0) {
        flags[0] = (fmask == 0ull) ? 1 : 0;  // 1 => floats are bf16
        flags[1] = (imask == 0ull) ? 1 : 0;  // 1 => ints are int64
    }
}

// ---------------- K0b: weight prep (transpose + bf16-ify) --------------------------------
// All *T layouts are [out_col][k] bf16 so B-fragments are contiguous 16B loads with the
// same k-mapping as A-fragments (k-permutation-robust).
__global__ __launch_bounds__(256) void k_wprep(
    const void* __restrict__ Wn, const void* __restrict__ Wea, const void* __restrict__ Wet,
    const void* __restrict__ Wup, const void* __restrict__ Wat,
    unsigned short* __restrict__ WnT, unsigned short* __restrict__ WeaT,
    unsigned short* __restrict__ WetT, unsigned short* __restrict__ Wu1T,
    unsigned short* __restrict__ Wu2T, unsigned short* __restrict__ WatMidT,
    unsigned short* __restrict__ WatTS, const int* __restrict__ flags)
{
    const bool isb = flags[0] != 0;
    int i = blockIdx.x * 256 + threadIdx.x;
    if (i < 3 * 128 * 256) {
        int ty = i >> 15, rem = i & 32767, c = rem >> 8, k = rem & 255;
        WnT[i] = f2bf(ldF(Wn, ((size_t)ty * 256 + k) * 128 + c, isb));
    }
    if (i < 128 * 128) {
        int c = i >> 7, k = i & 127;
        Wu1T[i] = f2bf(ldF(Wup, (size_t)k * 128 + c, isb));
        Wu2T[i] = f2bf(ldF(Wup, (size_t)(128 + k) * 128 + c, isb));
    }
    if (i < 128 * 64) {
        int c = i >> 6, k = i & 63;
        WeaT[i] = f2bf(ldF(Wea, (size_t)k * 128 + c, isb));
        WetT[i] = f2bf(ldF(Wet, (size_t)k * 128 + c, isb));
    }
    if (i < 16 * 256) {
        int c = i >> 8, k = i & 255;
        WatMidT[i] = (c < 8) ? f2bf(ldF(Wat, (size_t)(128 + k) * 8 + c, isb)) : (unsigned short)0;
    }
    if (i < 16 * 128) {
        int c = i >> 7, k = i & 127;
        WatTS[i] = (c < 8) ? f2bf(ldF(Wat, (size_t)k * 8 + c, isb))
                           : f2bf(ldF(Wat, (size_t)(384 + k) * 8 + (c - 8), isb));
    }
}

// ---------------- K1: node pipeline (MFMA): emb -> base, c_ts -----------------------------
__global__ __launch_bounds__(256) void k_node(
    const void* __restrict__ nf, const void* __restrict__ ntype,
    const unsigned short* __restrict__ WnT, const unsigned short* __restrict__ Wu1T,
    const unsigned short* __restrict__ WatTS,
    unsigned short* __restrict__ base, float* __restrict__ c_ts,
    const int* __restrict__ flags)
{
    const bool isb = flags[0] != 0, i64 = flags[1] != 0;
    const int t = threadIdx.x, lane = t & 63, wid = t >> 6;
    const int m = wid & 1, nh = wid >> 1;
    const int lr = lane & 15, lg = lane >> 4;
    const int n0 = blockIdx.x * 32;

    __shared__ __align__(16) unsigned short s_x[32 * 264];
    __shared__ __align__(16) unsigned short s_emb[32 * 136];
    __shared__ int s_ty[32];

    if (t < 32) {
        int nn = n0 + t;
        s_ty[t] = clampi(ldI(ntype, nn < N_NODES ? nn : N_NODES - 1, i64), 0, 2);
    }
    if (isb) {
        for (int i = t; i < 32 * 32; i += 256) {
            int r = i >> 5, c8 = (i & 31) * 8;
            bf16x8 v = (bf16x8)(short)0;
            if (n0 + r < N_NODES)
                v = *(const bf16x8*)((const unsigned short*)nf + (size_t)(n0 + r) * 256 + c8);
            *(bf16x8*)&s_x[r * 264 + c8] = v;
        }
    } else {
        for (int i = t; i < 32 * 64; i += 256) {
            int r = i >> 6, c4 = (i & 63) * 4;
            float4 v = make_float4(0.f, 0.f, 0.f, 0.f);
            if (n0 + r < N_NODES)
                v = *(const float4*)((const float*)nf + (size_t)(n0 + r) * 256 + c4);
            unsigned short* d = &s_x[r * 264 + c4];
            d[0] = f2bf(v.x); d[1] = f2bf(v.y); d[2] = f2bf(v.z); d[3] = f2bf(v.w);
        }
    }
    __syncthreads();

    // ---- Stage A: 3-type projection, K=256 ----
    bf16x8 A[8];
    #pragma unroll
    for (int ks = 0; ks < 8; ++ks)
        A[ks] = *(const bf16x8*)&s_x[(m * 16 + lr) * 264 + ks * 32 + lg * 8];

    f32x4 acc0[4], acc1[4], acc2[4];
    #pragma unroll
    for (int ct = 0; ct < 4; ++ct) {
        acc0[ct] = (f32x4)(0.f); acc1[ct] = (f32x4)(0.f); acc2[ct] = (f32x4)(0.f);
    }
    #pragma unroll
    for (int ct = 0; ct < 4; ++ct) {
        const int crow = nh * 64 + ct * 16 + lr;
        #pragma unroll
        for (int ks = 0; ks < 8; ++ks) {
            const int koff = ks * 32 + lg * 8;
            bf16x8 B0 = *(const bf16x8*)(WnT + (size_t)crow * 256 + koff);
            bf16x8 B1 = *(const bf16x8*)(WnT + (size_t)(128 + crow) * 256 + koff);
            bf16x8 B2 = *(const bf16x8*)(WnT + (size_t)(256 + crow) * 256 + koff);
            acc0[ct] = MFMA_BF16(A[ks], B0, acc0[ct], 0, 0, 0);
            acc1[ct] = MFMA_BF16(A[ks], B1, acc1[ct], 0, 0, 0);
            acc2[ct] = MFMA_BF16(A[ks], B2, acc2[ct], 0, 0, 0);
        }
    }
    #pragma unroll
    for (int ct = 0; ct < 4; ++ct) {
        const int col = nh * 64 + ct * 16 + lr;
        #pragma unroll
        for (int j = 0; j < 4; ++j) {
            const int row = m * 16 + lg * 4 + j;
            int ty = s_ty[row];
            float v = (ty == 0) ? acc0[ct][j] : ((ty == 1) ? acc1[ct][j] : acc2[ct][j]);
            s_emb[row * 136 + col] = f2bf(v);
        }
    }
    __syncthreads();

    // ---- Stage B: base = emb @ Wu1, K=128 ----
    bf16x8 A2[4];
    #pragma unroll
    for (int ks = 0; ks < 4; ++ks)
        A2[ks] = *(const bf16x8*)&s_emb[(m * 16 + lr) * 136 + ks * 32 + lg * 8];

    f32x4 accB[4];
    #pragma unroll
    for (int ct = 0; ct < 4; ++ct) accB[ct] = (f32x4)(0.f);
    #pragma unroll
    for (int ct = 0; ct < 4; ++ct) {
        const int crow = nh * 64 + ct * 16 + lr;
        #pragma unroll
        for (int ks = 0; ks < 4; ++ks) {
            bf16x8 B = *(const bf16x8*)(Wu1T + (size_t)crow * 128 + ks * 32 + lg * 8);
            accB[ct] = MFMA_BF16(A2[ks], B, accB[ct], 0, 0, 0);
        }
    }
    #pragma unroll
    for (int ct = 0; ct < 4; ++ct) {
        const int col = nh * 64 + ct * 16 + lr;
        #pragma unroll
        for (int j = 0; j < 4; ++j) {
            const int n = n0 + m * 16 + lg * 4 + j;
            if (n < N_NODES) base[(size_t)n * 128 + col] = f2bf(accB[ct][j]);
        }
    }

    // ---- Stage C: c_ts = emb @ WatTS (nh==0 waves) ----
    if (nh == 0) {
        f32x4 aS = (f32x4)(0.f);
        #pragma unroll
        for (int ks = 0; ks < 4; ++ks) {
            bf16x8 B = *(const bf16x8*)(WatTS + (size_t)lr * 128 + ks * 32 + lg * 8);
            aS = MFMA_BF16(A2[ks], B, aS, 0, 0, 0);
        }
        #pragma unroll
        for (int j = 0; j < 4; ++j) {
            const int n = n0 + m * 16 + lg * 4 + j;
            if (n < N_NODES) c_ts[(size_t)n * 16 + lr] = aS[j];
        }
    }
}

// ---------------- K2 helpers --------------------------------------------------------------
static __device__ __forceinline__ void load_afrag64(
    bf16x8 Af[2], const void* __restrict__ src, int arow, int lg, bool isb)
{
    #pragma unroll
    for (int ks = 0; ks < 2; ++ks) {
        const int koff = ks * 32 + lg * 8;
        if (isb) {
            Af[ks] = *(const bf16x8*)((const unsigned short*)src + (size_t)arow * 64 + koff);
        } else {
            const float* p = (const float*)src + (size_t)arow * 64 + koff;
            float4 a0 = *(const float4*)p, a1 = *(const float4*)(p + 4);
            bf16x8 v;
            v[0] = (short)f2bf(a0.x); v[1] = (short)f2bf(a0.y);
            v[2] = (short)f2bf(a0.z); v[3] = (short)f2bf(a0.w);
            v[4] = (short)f2bf(a1.x); v[5] = (short)f2bf(a1.y);
            v[6] = (short)f2bf(a1.z); v[7] = (short)f2bf(a1.w);
            Af[ks] = v;
        }
    }
}

// project [16 edges x 64] @ WT[128][64] -> lrelu -> s_buf rows (wave-private 16-row stripe)
static __device__ __forceinline__ void proj64_to_lds(
    const bf16x8 Af[2], const unsigned short* __restrict__ WT,
    unsigned short* __restrict__ s_buf, int m, int lr, int lg)
{
    #pragma unroll
    for (int half = 0; half < 2; ++half) {
        f32x4 acc[4];
        #pragma unroll
        for (int ct = 0; ct < 4; ++ct) acc[ct] = (f32x4)(0.f);
        #pragma unroll
        for (int ct = 0; ct < 4; ++ct) {
            const int crow = half * 64 + ct * 16 + lr;
            #pragma unroll
            for (int ks = 0; ks < 2; ++ks) {
                bf16x8 B = *(const bf16x8*)(WT + (size_t)crow * 64 + ks * 32 + lg * 8);
                acc[ct] = MFMA_BF16(Af[ks], B, acc[ct], 0, 0, 0);
            }
        }
        #pragma unroll
        for (int ct = 0; ct < 4; ++ct) {
            const int col = half * 64 + ct * 16 + lr;
            #pragma unroll
            for (int j = 0; j < 4; ++j)
                s_buf[(m * 16 + lg * 4 + j) * 132 + col] = f2bf(lrelu(acc[ct][j]));
        }
    }
}

// ---------------- K2: per-edge MFMA, BARRIER-FREE -----------------------------------------
// 32 edges/block, 128 threads = 2 waves; wave m owns edge rows [m*16, m*16+16) and LDS
// stripe rows [m*16, m*16+16). ALL LDS traffic is wave-private -> zero __syncthreads.
// Per-lane metadata (eidx/inv/c_ts) loaded directly from global at the top (broadcast
// addresses within lane groups -> L1 served), so every global load is in flight before
// the MFMA phases begin.
__global__ __launch_bounds__(128) void k_edge(
    const void* __restrict__ eattr, const void* __restrict__ etype,
    const void* __restrict__ eidx, const float* __restrict__ c_ts,
    const unsigned short* __restrict__ WeaT, const unsigned short* __restrict__ WetT,
    const unsigned short* __restrict__ Wu2T, const unsigned short* __restrict__ WatMidT,
    const int* __restrict__ inv, float* __restrict__ scores,
    unsigned short* __restrict__ ap, const int* __restrict__ flags)
{
    const bool isb = flags[0] != 0, i64 = flags[1] != 0;
    const int t = threadIdx.x, lane = t & 63, m = t >> 6;   // m in {0,1}
    const int lr = lane & 15, lg = lane >> 4;
    const int e0 = blockIdx.x * 32;

    __shared__ __align__(16) unsigned short s_buf[32 * 132];

    // ---- all global loads issued up front ----
    const int arow = e0 + m * 16 + lr;
    bf16x8 Aet[2], Aea[2];
    load_afrag64(Aet, etype, arow, lg, isb);
    load_afrag64(Aea, eattr, arow, lg, isb);

    int slotj[4], aslot[4];
    float ctj[4], csj[4];
    #pragma unroll
    for (int j = 0; j < 4; ++j) {
        const int rw = m * 16 + lg * 4 + j;         // score row (this lane's C-frag rows)
        const int ew = e0 + rw;
        int s = clampi(ldI(eidx, (size_t)ew, i64), 0, N_NODES - 1);
        int d = clampi(ldI(eidx, (size_t)N_EDGES + ew, i64), 0, N_NODES - 1);
        slotj[j] = clampi(inv[ew], 0, N_EDGES - 1);
        ctj[j] = c_ts[(size_t)d * 16 + (lr & 7)];        // tar contribution (head lr<8)
        csj[j] = c_ts[(size_t)s * 16 + 8 + (lr & 7)];    // src contribution
        const int rs = m * 16 + lg + j * 4;         // ap-store row (wave-private remap)
        aslot[j] = clampi(inv[e0 + rs], 0, N_EDGES - 1);
    }

    f32x4 aS = (f32x4)(0.f);

    // ---- phase A: te = lrelu(ET @ Wet) -> s_buf stripe ----
    proj64_to_lds(Aet, WetT, s_buf, m, lr, lg);
    // ---- phase B: score partial from te (k range 128..255 of WatMid) ----
    #pragma unroll
    for (int ks = 0; ks < 4; ++ks) {
        bf16x8 A = *(const bf16x8*)&s_buf[(m * 16 + lr) * 132 + ks * 32 + lg * 8];
        bf16x8 B = *(const bf16x8*)(WatMidT + (size_t)lr * 256 + 128 + ks * 32 + lg * 8);
        aS = MFMA_BF16(A, B, aS, 0, 0, 0);
    }
    // ---- phase C: ae = lrelu(EA @ Wea) -> s_buf stripe (in-wave order after B reads) ----
    proj64_to_lds(Aea, WeaT, s_buf, m, lr, lg);
    // ---- phase D: A2 from stripe; score partial from ae (k range 0..127) ----
    bf16x8 A2[4];
    #pragma unroll
    for (int ks = 0; ks < 4; ++ks)
        A2[ks] = *(const bf16x8*)&s_buf[(m * 16 + lr) * 132 + ks * 32 + lg * 8];
    #pragma unroll
    for (int ks = 0; ks < 4; ++ks) {
        bf16x8 B = *(const bf16x8*)(WatMidT + (size_t)lr * 256 + ks * 32 + lg * 8);
        aS = MFMA_BF16(A2[ks], B, aS, 0, 0, 0);
    }
    // ---- score finish + store ----
    if (lr < 8) {
        #pragma unroll
        for (int j = 0; j < 4; ++j)
            scores[(size_t)slotj[j] * 8 + lr] = lrelu(aS[j] + ctj[j] + csj[j]);
    }

    // ---- stage 2: ap = ae @ Wu2 -> s_buf stripe ----
    #pragma unroll
    for (int half = 0; half < 2; ++half) {
        f32x4 a2[4];
        #pragma unroll
        for (int ct = 0; ct < 4; ++ct) a2[ct] = (f32x4)(0.f);
        #pragma unroll
        for (int ct = 0; ct < 4; ++ct) {
            const int crow = half * 64 + ct * 16 + lr;
            #pragma unroll
            for (int ks = 0; ks < 4; ++ks) {
                bf16x8 B = *(const bf16x8*)(Wu2T + (size_t)crow * 128 + ks * 32 + lg * 8);
                a2[ct] = MFMA_BF16(A2[ks], B, a2[ct], 0, 0, 0);
            }
        }
        #pragma unroll
        for (int ct = 0; ct < 4; ++ct) {
            const int col = half * 64 + ct * 16 + lr;
            #pragma unroll
            for (int j = 0; j < 4; ++j)
                s_buf[(m * 16 + lg * 4 + j) * 132 + col] = f2bf(a2[ct][j]);
        }
    }
    // ---- coalesced ap store, wave-private rows: r = m*16 + lg + 4i ----
    #pragma unroll
    for (int i = 0; i < 4; ++i) {
        const int r = m * 16 + lg + i * 4;
        bf16x8 v = *(const bf16x8*)&s_buf[r * 132 + lr * 8];
        *(bf16x8*)(ap + (size_t)aslot[i] * 128 + lr * 8) = v;
    }
}

// ---------------- K3: CSR build over src --------------------------------------------------
__global__ void k_hist(const void* __restrict__ eidx, int* __restrict__ counts,
                       const int* __restrict__ flags)
{
    const bool i64 = flags[1] != 0;
    int e = blockIdx.x * blockDim.x + threadIdx.x;
    if (e < N_EDGES) atomicAdd(&counts[clampi(ldI(eidx, e, i64), 0, N_NODES - 1)], 1);
}

__global__ __launch_bounds__(256) void k_scan1(const int* __restrict__ counts,
                                               int* __restrict__ offsets, int* __restrict__ bsum)
{
    __shared__ int buf[256];
    int b = blockIdx.x, t = threadIdx.x, i = b * 256 + t;
    int v = (i < N_NODES) ? counts[i] : 0;
    buf[t] = v;
    __syncthreads();
    for (int d = 1; d < 256; d <<= 1) {
        int add = (t >= d) ? buf[t - d] : 0;
        __syncthreads();
        buf[t] += add;
        __syncthreads();
    }
    if (i < N_NODES) offsets[i] = buf[t] - v;
    if (t == 255) bsum[b] = buf[255];
}
__global__ __launch_bounds__(256) void k_scan2(int* __restrict__ bsum, int nb)
{
    __shared__ int buf[256];
    int t = threadIdx.x;
    int v = (t < nb) ? bsum[t] : 0;
    buf[t] = v;
    __syncthreads();
    for (int d = 1; d < 256; d <<= 1) {
        int add = (t >= d) ? buf[t - d] : 0;
        __syncthreads();
        buf[t] += add;
        __syncthreads();
    }
    if (t < nb) bsum[t] = buf[t] - v;
}
__global__ __launch_bounds__(256) void k_scan3(int* __restrict__ offsets,
                                               const int* __restrict__ bsum)
{
    int i = blockIdx.x * 256 + threadIdx.x;
    if (i < N_NODES) offsets[i] += bsum[i >> 8];
    if (i == 0) offsets[N_NODES] = N_EDGES;
}

// writes INVERSE permutation: inv[e] = CSR slot of edge e
__global__ void k_scatter(const void* __restrict__ eidx, const int* __restrict__ offsets,
                          int* __restrict__ fill, int* __restrict__ inv,
                          const int* __restrict__ flags)
{
    const bool i64 = flags[1] != 0;
    int e = blockIdx.x * blockDim.x + threadIdx.x;
    if (e >= N_EDGES) return;
    int s = clampi(ldI(eidx, e, i64), 0, N_NODES - 1);
    int p = atomicAdd(&fill[s], 1);
    inv[e] = offsets[s] + p;
}

// ---------------- K4: segment softmax in slot order (sequential reads) --------------------
__global__ void k_stats(float* __restrict__ scores, const int* __restrict__ offsets)
{
    int tid = blockIdx.x * blockDim.x + threadIdx.x;
    if (tid >= N_NODES * 8) return;
    int n = tid >> 3, h = tid & 7;
    int off = offsets[n], deg = offsets[n + 1] - off;
    if (deg <= 0) return;
    float m = -1e30f;
    for (int j = 0; j < deg; ++j)
        m = fmaxf(m, scores[(size_t)(off + j) * 8 + h]);
    float d = 0.f;
    for (int j = 0; j < deg; ++j)
        d += expf(scores[(size_t)(off + j) * 8 + h] - m);
    float inv = (d > 0.f) ? 1.f / d : 0.f;
    for (int j = 0; j < deg; ++j) {
        size_t idx = (size_t)(off + j) * 8 + h;
        scores[idx] = expf(scores[idx] - m) * inv;
    }
}

// ---------------- K5: per-node aggregation, vectorized (8 nodes/block, 32 lanes/node) -----
// lane covers cols [4c, 4c+4); ap loads are ushort4 (8B/lane), out stores ushort4/float4.
// No LDS, no barriers; node groups within a wave diverge only to max(deg) iterations.
__global__ __launch_bounds__(256) void k_aggr3(
    const unsigned short* __restrict__ base, const float* __restrict__ attn,
    const unsigned short* __restrict__ ap, const int* __restrict__ offsets,
    void* __restrict__ out, const int* __restrict__ flags)
{
    const bool isb = flags[0] != 0;
    const int n = blockIdx.x * 8 + (threadIdx.x >> 5);   // N_NODES % 8 == 0
    const int c = threadIdx.x & 31;                      // col group: 4c..4c+3

    ushort4 b4 = *(const ushort4*)(base + (size_t)n * 128 + 4 * c);
    float b0 = u2f(b4.x), b1 = u2f(b4.y), b2 = u2f(b4.z), b3 = u2f(b4.w);

    float acc[8][4];
    #pragma unroll
    for (int h = 0; h < 8; ++h)
        #pragma unroll
        for (int k = 0; k < 4; ++k) acc[h][k] = 0.f;

    const int off = offsets[n], deg = offsets[n + 1] - off;
    for (int j = 0; j < deg; ++j) {
        const size_t slot = (size_t)(off + j);
        ushort4 v = *(const ushort4*)(ap + slot * 128 + 4 * c);
        float m0 = lrelu(b0 + u2f(v.x));
        float m1 = lrelu(b1 + u2f(v.y));
        float m2 = lrelu(b2 + u2f(v.z));
        float m3 = lrelu(b3 + u2f(v.w));
        const float* at = attn + slot * 8;   // 32B line, broadcast across lanes
        #pragma unroll
        for (int h = 0; h < 8; ++h) {
            float a = at[h];
            acc[h][0] += a * m0; acc[h][1] += a * m1;
            acc[h][2] += a * m2; acc[h][3] += a * m3;
        }
    }
    if (isb) {
        __hip_bfloat16* o = (__hip_bfloat16*)out;
        #pragma unroll
        for (int h = 0; h < 8; ++h) {
            ushort4 o4;
            o4.x = f2bf(acc[h][0]); o4.y = f2bf(acc[h][1]);
            o4.z = f2bf(acc[h][2]); o4.w = f2bf(acc[h][3]);
            *(ushort4*)((unsigned short*)o + (size_t)n * 1024 + h * 128 + 4 * c) = o4;
        }
    } else {
        float* o = (float*)out;
        #pragma unroll
        for (int h = 0; h < 8; ++h) {
            float4 o4 = make_float4(acc[h][0], acc[h][1], acc[h][2], acc[h][3]);
            *(float4*)(o + (size_t)n * 1024 + h * 128 + 4 * c) = o4;
        }
    }
}

// ---------------- launcher ----------------------------------------------------------------
static inline size_t alignup(size_t x, size_t a) { return (x + a - 1) & ~(a - 1); }

extern "C" void kernel_launch(void* const* d_in, const int* in_sizes, int n_in,
                              void* d_out, int out_size, void* d_ws, size_t ws_size,
                              hipStream_t stream)
{
    const void* nf   = d_in[0];
    const void* eidx = d_in[1];
    const void* eatt = d_in[2];
    const void* etyp = d_in[3];
    const void* ntyp = d_in[4];
    // d_in[5] edge_type_list: unused by the reference
    const void* Wn   = d_in[6];
    const void* Wea  = d_in[7];
    const void* Wet  = d_in[8];
    const void* Wup  = d_in[9];
    const void* Wat  = d_in[10];

    // workspace layout (~133.5 MB, same footprint as verified rounds)
    char* w = (char*)d_ws;
    size_t off = 16;
    int* flags = (int*)w;
    unsigned short* base = (unsigned short*)(w + off);  off += (size_t)N_NODES * 128 * 2;
    float* c_ts   = (float*)(w + off);                  off += (size_t)N_NODES * 16 * 4;
    float* scores = (float*)(w + off);                  off += (size_t)N_EDGES * 8 * 4;
    int* counts   = (int*)(w + off);                    off += (size_t)N_NODES * 4;
    int* offsets  = (int*)(w + off);                    off += (size_t)(N_NODES + 1) * 4;
    int* inv      = (int*)(w + off);                    off += (size_t)N_EDGES * 4;
    int* bsum     = (int*)(w + off);                    off += 1024;
    off = alignup(off, 16);
    unsigned short* WnT     = (unsigned short*)(w + off); off += (size_t)3 * 128 * 256 * 2;
    unsigned short* WeaT    = (unsigned short*)(w + off); off += 128 * 64 * 2;
    unsigned short* WetT    = (unsigned short*)(w + off); off += 128 * 64 * 2;
    unsigned short* Wu1T    = (unsigned short*)(w + off); off += 128 * 128 * 2;
    unsigned short* Wu2T    = (unsigned short*)(w + off); off += 128 * 128 * 2;
    unsigned short* WatMidT = (unsigned short*)(w + off); off += 16 * 256 * 2;
    unsigned short* WatTS   = (unsigned short*)(w + off); off += 16 * 128 * 2;
    off = alignup(off, 16);
    unsigned short* ap = (unsigned short*)(w + off);

    hipMemsetAsync(counts, 0, N_NODES * sizeof(int), stream);

    k_detect<<<1, 64, 0, stream>>>(nf, eidx, flags);
    k_wprep<<<384, 256, 0, stream>>>(Wn, Wea, Wet, Wup, Wat,
                                     WnT, WeaT, WetT, Wu1T, Wu2T, WatMidT, WatTS, flags);
    // CSR first (so k_edge can scatter outputs to slots)
    k_hist<<<(N_EDGES + 255) / 256, 256, 0, stream>>>(eidx, counts, flags);
    const int SB = (N_NODES + 255) / 256;
    k_scan1<<<SB, 256, 0, stream>>>(counts, offsets, bsum);
    k_scan2<<<1, 256, 0, stream>>>(bsum, SB);
    k_scan3<<<SB, 256, 0, stream>>>(offsets, bsum);
    hipMemsetAsync(counts, 0, N_NODES * sizeof(int), stream);   // reuse counts as fill
    k_scatter<<<(N_EDGES + 255) / 256, 256, 0, stream>>>(eidx, offsets, counts, inv, flags);

    k_node<<<(N_NODES + 31) / 32, 256, 0, stream>>>(nf, ntyp, WnT, Wu1T, WatTS,
                                                    base, c_ts, flags);
    k_edge<<<N_EDGES / 32, 128, 0, stream>>>(eatt, etyp, eidx, c_ts,
                                             WeaT, WetT, Wu2T, WatMidT,
                                             inv, scores, ap, flags);
    k_stats<<<(N_NODES * 8 + 255) / 256, 256, 0, stream>>>(scores, offsets);
    k_aggr3<<<N_NODES / 8, 256, 0, stream>>>(base, scores, ap, offsets, d_out, flags);
}

// Round 5
// 780.548 us; speedup vs baseline: 4.8217x; 1.0412x over previous
//
#include <hip/hip_runtime.h>
#include <hip/hip_bf16.h>

#define N_NODES 50000
#define N_EDGES 400000
#define SLOPE 0.2f

typedef __attribute__((ext_vector_type(8))) short bf16x8;   // 8 bf16 = 4 VGPR (MFMA A/B frag)
typedef __attribute__((ext_vector_type(4))) float f32x4;    // MFMA C/D frag
#define MFMA_BF16 __builtin_amdgcn_mfma_f32_16x16x32_bf16

static __device__ __forceinline__ float lrelu(float x) { return x >= 0.f ? x : SLOPE * x; }
static __device__ __forceinline__ float b2f(__hip_bfloat16 x) { return __bfloat162float(x); }
static __device__ __forceinline__ float u2f(unsigned short u) {
    union { unsigned short u; __hip_bfloat16 b; } cv; cv.u = u; return __bfloat162float(cv.b);
}
static __device__ __forceinline__ unsigned short f2bf(float x) {
    union { __hip_bfloat16 b; unsigned short u; } cv; cv.b = __float2bfloat16(x); return cv.u;
}
static __device__ __forceinline__ int clampi(int v, int lo, int hi) {
    return v < lo ? lo : (v > hi ? hi : v);
}
// dual-dtype float load: isb ? bf16 : f32
static __device__ __forceinline__ float ldF(const void* __restrict__ p, size_t i, bool isb) {
    return isb ? b2f(((const __hip_bfloat16*)p)[i]) : ((const float*)p)[i];
}
// dual-width index load: i64 ? int64 : int32
static __device__ __forceinline__ int ldI(const void* __restrict__ p, size_t i, bool i64) {
    return i64 ? (int)(((const long long*)p)[i]) : ((const int*)p)[i];
}

// ---------------- K0: dtype detection ----------------------------------------------------
__global__ void k_detect(const void* __restrict__ nf, const void* __restrict__ eidx,
                         int* __restrict__ flags)
{
    int t = threadIdx.x;  // 64 threads
    float x = b2f(((const __hip_bfloat16*)nf)[2 * t]);
    bool bad = !(x == x) || fabsf(x) > 1e4f;
    unsigned long long fmask = __ballot(bad);
    int v = ((const int*)eidx)[2 * t + 1];
    unsigned long long imask = __ballot(v != 0);
    if (t == 0) {
        flags[0] = (fmask == 0ull) ? 1 : 0;  // 1 => floats are bf16
        flags[1] = (imask == 0ull) ? 1 : 0;  // 1 => ints are int64
    }
}

// ---------------- K0b: weight prep (transpose + bf16-ify) + zero counts -------------------
__global__ __launch_bounds__(256) void k_wprep(
    const void* __restrict__ Wn, const void* __restrict__ Wea, const void* __restrict__ Wet,
    const void* __restrict__ Wup, const void* __restrict__ Wat,
    unsigned short* __restrict__ WnT, unsigned short* __restrict__ WeaT,
    unsigned short* __restrict__ WetT, unsigned short* __restrict__ Wu1T,
    unsigned short* __restrict__ Wu2T, unsigned short* __restrict__ WatMidT,
    unsigned short* __restrict__ WatTS, int* __restrict__ counts,
    const int* __restrict__ flags)
{
    const bool isb = flags[0] != 0;
    int i = blockIdx.x * 256 + threadIdx.x;
    if (i < N_NODES) counts[i] = 0;
    if (i < 3 * 128 * 256) {
        int ty = i >> 15, rem = i & 32767, c = rem >> 8, k = rem & 255;
        WnT[i] = f2bf(ldF(Wn, ((size_t)ty * 256 + k) * 128 + c, isb));
    }
    if (i < 128 * 128) {
        int c = i >> 7, k = i & 127;
        Wu1T[i] = f2bf(ldF(Wup, (size_t)k * 128 + c, isb));
        Wu2T[i] = f2bf(ldF(Wup, (size_t)(128 + k) * 128 + c, isb));
    }
    if (i < 128 * 64) {
        int c = i >> 6, k = i & 63;
        WeaT[i] = f2bf(ldF(Wea, (size_t)k * 128 + c, isb));
        WetT[i] = f2bf(ldF(Wet, (size_t)k * 128 + c, isb));
    }
    if (i < 16 * 256) {
        int c = i >> 8, k = i & 255;
        WatMidT[i] = (c < 8) ? f2bf(ldF(Wat, (size_t)(128 + k) * 8 + c, isb)) : (unsigned short)0;
    }
    if (i < 16 * 128) {
        int c = i >> 7, k = i & 127;
        WatTS[i] = (c < 8) ? f2bf(ldF(Wat, (size_t)k * 8 + c, isb))
                           : f2bf(ldF(Wat, (size_t)(384 + k) * 8 + (c - 8), isb));
    }
}

// ---------------- K1: node pipeline (MFMA): emb -> base, c_ts -----------------------------
__global__ __launch_bounds__(256) void k_node(
    const void* __restrict__ nf, const void* __restrict__ ntype,
    const unsigned short* __restrict__ WnT, const unsigned short* __restrict__ Wu1T,
    const unsigned short* __restrict__ WatTS,
    unsigned short* __restrict__ base, float* __restrict__ c_ts,
    const int* __restrict__ flags)
{
    const bool isb = flags[0] != 0, i64 = flags[1] != 0;
    const int t = threadIdx.x, lane = t & 63, wid = t >> 6;
    const int m = wid & 1, nh = wid >> 1;
    const int lr = lane & 15, lg = lane >> 4;
    const int n0 = blockIdx.x * 32;

    __shared__ __align__(16) unsigned short s_x[32 * 264];
    __shared__ __align__(16) unsigned short s_emb[32 * 136];
    __shared__ int s_ty[32];

    if (t < 32) {
        int nn = n0 + t;
        s_ty[t] = clampi(ldI(ntype, nn < N_NODES ? nn : N_NODES - 1, i64), 0, 2);
    }
    if (isb) {
        for (int i = t; i < 32 * 32; i += 256) {
            int r = i >> 5, c8 = (i & 31) * 8;
            bf16x8 v = (bf16x8)(short)0;
            if (n0 + r < N_NODES)
                v = *(const bf16x8*)((const unsigned short*)nf + (size_t)(n0 + r) * 256 + c8);
            *(bf16x8*)&s_x[r * 264 + c8] = v;
        }
    } else {
        for (int i = t; i < 32 * 64; i += 256) {
            int r = i >> 6, c4 = (i & 63) * 4;
            float4 v = make_float4(0.f, 0.f, 0.f, 0.f);
            if (n0 + r < N_NODES)
                v = *(const float4*)((const float*)nf + (size_t)(n0 + r) * 256 + c4);
            unsigned short* d = &s_x[r * 264 + c4];
            d[0] = f2bf(v.x); d[1] = f2bf(v.y); d[2] = f2bf(v.z); d[3] = f2bf(v.w);
        }
    }
    __syncthreads();

    // ---- Stage A: 3-type projection, K=256 ----
    bf16x8 A[8];
    #pragma unroll
    for (int ks = 0; ks < 8; ++ks)
        A[ks] = *(const bf16x8*)&s_x[(m * 16 + lr) * 264 + ks * 32 + lg * 8];

    f32x4 acc0[4], acc1[4], acc2[4];
    #pragma unroll
    for (int ct = 0; ct < 4; ++ct) {
        acc0[ct] = (f32x4)(0.f); acc1[ct] = (f32x4)(0.f); acc2[ct] = (f32x4)(0.f);
    }
    #pragma unroll
    for (int ct = 0; ct < 4; ++ct) {
        const int crow = nh * 64 + ct * 16 + lr;
        #pragma unroll
        for (int ks = 0; ks < 8; ++ks) {
            const int koff = ks * 32 + lg * 8;
            bf16x8 B0 = *(const bf16x8*)(WnT + (size_t)crow * 256 + koff);
            bf16x8 B1 = *(const bf16x8*)(WnT + (size_t)(128 + crow) * 256 + koff);
            bf16x8 B2 = *(const bf16x8*)(WnT + (size_t)(256 + crow) * 256 + koff);
            acc0[ct] = MFMA_BF16(A[ks], B0, acc0[ct], 0, 0, 0);
            acc1[ct] = MFMA_BF16(A[ks], B1, acc1[ct], 0, 0, 0);
            acc2[ct] = MFMA_BF16(A[ks], B2, acc2[ct], 0, 0, 0);
        }
    }
    #pragma unroll
    for (int ct = 0; ct < 4; ++ct) {
        const int col = nh * 64 + ct * 16 + lr;
        #pragma unroll
        for (int j = 0; j < 4; ++j) {
            const int row = m * 16 + lg * 4 + j;
            int ty = s_ty[row];
            float v = (ty == 0) ? acc0[ct][j] : ((ty == 1) ? acc1[ct][j] : acc2[ct][j]);
            s_emb[row * 136 + col] = f2bf(v);
        }
    }
    __syncthreads();

    // ---- Stage B: base = emb @ Wu1, K=128 ----
    bf16x8 A2[4];
    #pragma unroll
    for (int ks = 0; ks < 4; ++ks)
        A2[ks] = *(const bf16x8*)&s_emb[(m * 16 + lr) * 136 + ks * 32 + lg * 8];

    f32x4 accB[4];
    #pragma unroll
    for (int ct = 0; ct < 4; ++ct) accB[ct] = (f32x4)(0.f);
    #pragma unroll
    for (int ct = 0; ct < 4; ++ct) {
        const int crow = nh * 64 + ct * 16 + lr;
        #pragma unroll
        for (int ks = 0; ks < 4; ++ks) {
            bf16x8 B = *(const bf16x8*)(Wu1T + (size_t)crow * 128 + ks * 32 + lg * 8);
            accB[ct] = MFMA_BF16(A2[ks], B, accB[ct], 0, 0, 0);
        }
    }
    #pragma unroll
    for (int ct = 0; ct < 4; ++ct) {
        const int col = nh * 64 + ct * 16 + lr;
        #pragma unroll
        for (int j = 0; j < 4; ++j) {
            const int n = n0 + m * 16 + lg * 4 + j;
            if (n < N_NODES) base[(size_t)n * 128 + col] = f2bf(accB[ct][j]);
        }
    }

    // ---- Stage C: c_ts = emb @ WatTS (nh==0 waves) ----
    if (nh == 0) {
        f32x4 aS = (f32x4)(0.f);
        #pragma unroll
        for (int ks = 0; ks < 4; ++ks) {
            bf16x8 B = *(const bf16x8*)(WatTS + (size_t)lr * 128 + ks * 32 + lg * 8);
            aS = MFMA_BF16(A2[ks], B, aS, 0, 0, 0);
        }
        #pragma unroll
        for (int j = 0; j < 4; ++j) {
            const int n = n0 + m * 16 + lg * 4 + j;
            if (n < N_NODES) c_ts[(size_t)n * 16 + lr] = aS[j];
        }
    }
}

// ---------------- K2 helpers --------------------------------------------------------------
static __device__ __forceinline__ void load_afrag64(
    bf16x8 Af[2], const void* __restrict__ src, int arow, int lg, bool isb)
{
    #pragma unroll
    for (int ks = 0; ks < 2; ++ks) {
        const int koff = ks * 32 + lg * 8;
        if (isb) {
            Af[ks] = *(const bf16x8*)((const unsigned short*)src + (size_t)arow * 64 + koff);
        } else {
            const float* p = (const float*)src + (size_t)arow * 64 + koff;
            float4 a0 = *(const float4*)p, a1 = *(const float4*)(p + 4);
            bf16x8 v;
            v[0] = (short)f2bf(a0.x); v[1] = (short)f2bf(a0.y);
            v[2] = (short)f2bf(a0.z); v[3] = (short)f2bf(a0.w);
            v[4] = (short)f2bf(a1.x); v[5] = (short)f2bf(a1.y);
            v[6] = (short)f2bf(a1.z); v[7] = (short)f2bf(a1.w);
            Af[ks] = v;
        }
    }
}

// swizzled LDS-weight B-frag pointer: region at s_w + base (shorts), row-major rowlen=64,
// byte_off ^= (row&7)<<4 spreads the 16B column-slice across 8 line slots (balanced banks)
static __device__ __forceinline__ const bf16x8* ldsB64(
    const unsigned short* __restrict__ s_w, int base, int row, int k)
{
    int byte = ((base + row * 64 + k) << 1) ^ ((row & 7) << 4);
    return (const bf16x8*)((const char*)s_w + byte);
}

// project [16 edges x 64] @ LDS-weights[128][64] -> lrelu -> s_buf stripe rows
static __device__ __forceinline__ void proj64_lds(
    const bf16x8 Af[2], const unsigned short* __restrict__ s_w, int wbase,
    unsigned short* __restrict__ s_buf, int w, int lr, int lg)
{
    #pragma unroll
    for (int half = 0; half < 2; ++half) {
        f32x4 acc[4];
        #pragma unroll
        for (int ct = 0; ct < 4; ++ct) acc[ct] = (f32x4)(0.f);
        #pragma unroll
        for (int ct = 0; ct < 4; ++ct) {
            const int crow = half * 64 + ct * 16 + lr;
            #pragma unroll
            for (int ks = 0; ks < 2; ++ks) {
                bf16x8 B = *ldsB64(s_w, wbase, crow, ks * 32 + lg * 8);
                acc[ct] = MFMA_BF16(Af[ks], B, acc[ct], 0, 0, 0);
            }
        }
        #pragma unroll
        for (int ct = 0; ct < 4; ++ct) {
            const int col = half * 64 + ct * 16 + lr;
            #pragma unroll
            for (int j = 0; j < 4; ++j)
                s_buf[(w * 16 + lg * 4 + j) * 132 + col] = f2bf(lrelu(acc[ct][j]));
        }
    }
}

// ---------------- K2: per-edge MFMA; proj weights staged in LDS ---------------------------
// 64 edges/block, 256 threads = 4 waves; wave w owns edge rows [w*16, w*16+16) and the
// matching s_buf stripe. ONE barrier (after weight staging); the phase pipeline is
// wave-private. WeaT/WetT (32 KB) live in swizzled LDS -> B-frag loads are ds_read_b128
// instead of ~250-cycle L2 hits. Wu2T+WatMidT (40 KB) stay global (sole L1 tenants).
__global__ __launch_bounds__(256) void k_edge(
    const void* __restrict__ eattr, const void* __restrict__ etype,
    const void* __restrict__ eidx, const float* __restrict__ c_ts,
    const unsigned short* __restrict__ WeaT, const unsigned short* __restrict__ WetT,
    const unsigned short* __restrict__ Wu2T, const unsigned short* __restrict__ WatMidT,
    const int* __restrict__ inv, float* __restrict__ scores,
    unsigned short* __restrict__ ap, const int* __restrict__ flags)
{
    const bool isb = flags[0] != 0, i64 = flags[1] != 0;
    const int t = threadIdx.x, lane = t & 63, w = t >> 6;   // w in {0..3}
    const int lr = lane & 15, lg = lane >> 4;
    const int e0 = blockIdx.x * 64;

    __shared__ __align__(16) unsigned short s_w[16384];      // [0:8192)=WeaT, [8192:16384)=WetT
    __shared__ __align__(16) unsigned short s_buf[64 * 132];

    // ---- per-wave global loads issued first (overlap with staging) ----
    const int arow = e0 + w * 16 + lr;
    bf16x8 Aet[2], Aea[2];
    load_afrag64(Aet, etype, arow, lg, isb);
    load_afrag64(Aea, eattr, arow, lg, isb);

    int slotj[4], aslot[4];
    float ctj[4], csj[4];
    #pragma unroll
    for (int j = 0; j < 4; ++j) {
        const int rw = w * 16 + lg * 4 + j;         // score row (this lane's C-frag rows)
        const int ew = e0 + rw;
        int s = clampi(ldI(eidx, (size_t)ew, i64), 0, N_NODES - 1);
        int d = clampi(ldI(eidx, (size_t)N_EDGES + ew, i64), 0, N_NODES - 1);
        slotj[j] = clampi(inv[ew], 0, N_EDGES - 1);
        ctj[j] = c_ts[(size_t)d * 16 + (lr & 7)];        // tar contribution
        csj[j] = c_ts[(size_t)s * 16 + 8 + (lr & 7)];    // src contribution
        const int rs = w * 16 + lg + j * 4;         // ap-store row (wave-private remap)
        aslot[j] = clampi(inv[e0 + rs], 0, N_EDGES - 1);
    }

    // ---- stage WeaT||WetT into LDS, swizzled (2048 x 16B) ----
    for (int i = t; i < 2048; i += 256) {
        int src = i >> 10;                 // 0=Wea, 1=Wet
        int g = (i & 1023) * 8;            // short offset within 8192
        int row = g >> 6;
        bf16x8 v = *(const bf16x8*)((src ? WetT : WeaT) + g);
        int byte = (((src << 13) + g) << 1) ^ ((row & 7) << 4);
        *(bf16x8*)((char*)s_w + byte) = v;
    }
    __syncthreads();                       // weights visible to all waves

    f32x4 aS = (f32x4)(0.f);

    // ---- phase A: te = lrelu(ET @ Wet) -> s_buf stripe ----
    proj64_lds(Aet, s_w, 8192, s_buf, w, lr, lg);
    // ---- phase B: score partial from te (k range 128..255 of WatMid, global/L1) ----
    #pragma unroll
    for (int ks = 0; ks < 4; ++ks) {
        bf16x8 A = *(const bf16x8*)&s_buf[(w * 16 + lr) * 132 + ks * 32 + lg * 8];
        bf16x8 B = *(const bf16x8*)(WatMidT + (size_t)lr * 256 + 128 + ks * 32 + lg * 8);
        aS = MFMA_BF16(A, B, aS, 0, 0, 0);
    }
    // ---- phase C: ae = lrelu(EA @ Wea) -> s_buf stripe ----
    proj64_lds(Aea, s_w, 0, s_buf, w, lr, lg);
    // ---- phase D: A2 from stripe; score partial from ae (k range 0..127) ----
    bf16x8 A2[4];
    #pragma unroll
    for (int ks = 0; ks < 4; ++ks)
        A2[ks] = *(const bf16x8*)&s_buf[(w * 16 + lr) * 132 + ks * 32 + lg * 8];
    #pragma unroll
    for (int ks = 0; ks < 4; ++ks) {
        bf16x8 B = *(const bf16x8*)(WatMidT + (size_t)lr * 256 + ks * 32 + lg * 8);
        aS = MFMA_BF16(A2[ks], B, aS, 0, 0, 0);
    }
    // ---- score finish + store ----
    if (lr < 8) {
        #pragma unroll
        for (int j = 0; j < 4; ++j)
            scores[(size_t)slotj[j] * 8 + lr] = lrelu(aS[j] + ctj[j] + csj[j]);
    }

    // ---- stage 2: ap = ae @ Wu2 (Wu2 global/L1) -> s_buf stripe ----
    #pragma unroll
    for (int half = 0; half < 2; ++half) {
        f32x4 a2[4];
        #pragma unroll
        for (int ct = 0; ct < 4; ++ct) a2[ct] = (f32x4)(0.f);
        #pragma unroll
        for (int ct = 0; ct < 4; ++ct) {
            const int crow = half * 64 + ct * 16 + lr;
            #pragma unroll
            for (int ks = 0; ks < 4; ++ks) {
                bf16x8 B = *(const bf16x8*)(Wu2T + (size_t)crow * 128 + ks * 32 + lg * 8);
                a2[ct] = MFMA_BF16(A2[ks], B, a2[ct], 0, 0, 0);
            }
        }
        #pragma unroll
        for (int ct = 0; ct < 4; ++ct) {
            const int col = half * 64 + ct * 16 + lr;
            #pragma unroll
            for (int j = 0; j < 4; ++j)
                s_buf[(w * 16 + lg * 4 + j) * 132 + col] = f2bf(a2[ct][j]);
        }
    }
    // ---- coalesced ap store, wave-private rows: r = w*16 + lg + 4i ----
    #pragma unroll
    for (int i = 0; i < 4; ++i) {
        const int r = w * 16 + lg + i * 4;
        bf16x8 v = *(const bf16x8*)&s_buf[r * 132 + lr * 8];
        *(bf16x8*)(ap + (size_t)aslot[i] * 128 + lr * 8) = v;
    }
}

// ---------------- K3: CSR build over src --------------------------------------------------
__global__ void k_hist(const void* __restrict__ eidx, int* __restrict__ counts,
                       const int* __restrict__ flags)
{
    const bool i64 = flags[1] != 0;
    int e = blockIdx.x * blockDim.x + threadIdx.x;
    if (e < N_EDGES) atomicAdd(&counts[clampi(ldI(eidx, e, i64), 0, N_NODES - 1)], 1);
}

__global__ __launch_bounds__(256) void k_scan1(const int* __restrict__ counts,
                                               int* __restrict__ offsets, int* __restrict__ bsum)
{
    __shared__ int buf[256];
    int b = blockIdx.x, t = threadIdx.x, i = b * 256 + t;
    int v = (i < N_NODES) ? counts[i] : 0;
    buf[t] = v;
    __syncthreads();
    for (int d = 1; d < 256; d <<= 1) {
        int add = (t >= d) ? buf[t - d] : 0;
        __syncthreads();
        buf[t] += add;
        __syncthreads();
    }
    if (i < N_NODES) offsets[i] = buf[t] - v;
    if (t == 255) bsum[b] = buf[255];
}
__global__ __launch_bounds__(256) void k_scan2(int* __restrict__ bsum, int nb)
{
    __shared__ int buf[256];
    int t = threadIdx.x;
    int v = (t < nb) ? bsum[t] : 0;
    buf[t] = v;
    __syncthreads();
    for (int d = 1; d < 256; d <<= 1) {
        int add = (t >= d) ? buf[t - d] : 0;
        __syncthreads();
        buf[t] += add;
        __syncthreads();
    }
    if (t < nb) bsum[t] = buf[t] - v;
}
// also zeroes counts (reused as "fill" by k_scatter)
__global__ __launch_bounds__(256) void k_scan3(int* __restrict__ offsets,
                                               const int* __restrict__ bsum,
                                               int* __restrict__ counts)
{
    int i = blockIdx.x * 256 + threadIdx.x;
    if (i < N_NODES) {
        offsets[i] += bsum[i >> 8];
        counts[i] = 0;
    }
    if (i == 0) offsets[N_NODES] = N_EDGES;
}

// writes INVERSE permutation: inv[e] = CSR slot of edge e
__global__ void k_scatter(const void* __restrict__ eidx, const int* __restrict__ offsets,
                          int* __restrict__ fill, int* __restrict__ inv,
                          const int* __restrict__ flags)
{
    const bool i64 = flags[1] != 0;
    int e = blockIdx.x * blockDim.x + threadIdx.x;
    if (e >= N_EDGES) return;
    int s = clampi(ldI(eidx, e, i64), 0, N_NODES - 1);
    int p = atomicAdd(&fill[s], 1);
    inv[e] = offsets[s] + p;
}

// ---------------- K5: aggregation with FUSED segment softmax ------------------------------
// 8 nodes/block, 32 lanes/node, lane covers cols [4c,4c+4). Lanes 0..7 own head h=c:
// pre-pass computes max/denominator over the node's CSR slot range (sequential reads),
// main loop broadcasts per-edge attn weights via __shfl(width=32). No stats kernel,
// no attn array round-trip.
__global__ __launch_bounds__(256) void k_aggr4(
    const unsigned short* __restrict__ base, const float* __restrict__ scores,
    const unsigned short* __restrict__ ap, const int* __restrict__ offsets,
    void* __restrict__ out, const int* __restrict__ flags)
{
    const bool isb = flags[0] != 0;
    const int n = blockIdx.x * 8 + (threadIdx.x >> 5);   // N_NODES % 8 == 0
    const int c = threadIdx.x & 31;                      // col group: 4c..4c+3

    const int off = offsets[n], deg = offsets[n + 1] - off;

    // softmax stats on lanes 0..7 (h = c)
    float m = -1e30f, dsum = 0.f;
    if (c < 8) {
        for (int j = 0; j < deg; ++j)
            m = fmaxf(m, scores[(size_t)(off + j) * 8 + c]);
        for (int j = 0; j < deg; ++j)
            dsum += expf(scores[(size_t)(off + j) * 8 + c] - m);
    }
    const float sinv = (dsum > 0.f) ? 1.f / dsum : 0.f;

    ushort4 b4 = *(const ushort4*)(base + (size_t)n * 128 + 4 * c);
    float b0 = u2f(b4.x), b1 = u2f(b4.y), b2 = u2f(b4.z), b3 = u2f(b4.w);

    float acc[8][4];
    #pragma unroll
    for (int h = 0; h < 8; ++h)
        #pragma unroll
        for (int k = 0; k < 4; ++k) acc[h][k] = 0.f;

    for (int j = 0; j < deg; ++j) {
        const size_t slot = (size_t)(off + j);
        ushort4 v = *(const ushort4*)(ap + slot * 128 + 4 * c);
        float wgt = 0.f;
        if (c < 8) wgt = expf(scores[slot * 8 + c] - m) * sinv;
        float m0 = lrelu(b0 + u2f(v.x));
        float m1 = lrelu(b1 + u2f(v.y));
        float m2 = lrelu(b2 + u2f(v.z));
        float m3 = lrelu(b3 + u2f(v.w));
        #pragma unroll
        for (int h = 0; h < 8; ++h) {
            float a = __shfl(wgt, h, 32);
            acc[h][0] += a * m0; acc[h][1] += a * m1;
            acc[h][2] += a * m2; acc[h][3] += a * m3;
        }
    }
    if (isb) {
        __hip_bfloat16* o = (__hip_bfloat16*)out;
        #pragma unroll
        for (int h = 0; h < 8; ++h) {
            ushort4 o4;
            o4.x = f2bf(acc[h][0]); o4.y = f2bf(acc[h][1]);
            o4.z = f2bf(acc[h][2]); o4.w = f2bf(acc[h][3]);
            *(ushort4*)((unsigned short*)o + (size_t)n * 1024 + h * 128 + 4 * c) = o4;
        }
    } else {
        float* o = (float*)out;
        #pragma unroll
        for (int h = 0; h < 8; ++h) {
            float4 o4 = make_float4(acc[h][0], acc[h][1], acc[h][2], acc[h][3]);
            *(float4*)(o + (size_t)n * 1024 + h * 128 + 4 * c) = o4;
        }
    }
}

// ---------------- launcher ----------------------------------------------------------------
static inline size_t alignup(size_t x, size_t a) { return (x + a - 1) & ~(a - 1); }

extern "C" void kernel_launch(void* const* d_in, const int* in_sizes, int n_in,
                              void* d_out, int out_size, void* d_ws, size_t ws_size,
                              hipStream_t stream)
{
    const void* nf   = d_in[0];
    const void* eidx = d_in[1];
    const void* eatt = d_in[2];
    const void* etyp = d_in[3];
    const void* ntyp = d_in[4];
    // d_in[5] edge_type_list: unused by the reference
    const void* Wn   = d_in[6];
    const void* Wea  = d_in[7];
    const void* Wet  = d_in[8];
    const void* Wup  = d_in[9];
    const void* Wat  = d_in[10];

    // workspace layout (~133.5 MB, same footprint as verified rounds)
    char* w = (char*)d_ws;
    size_t off = 16;
    int* flags = (int*)w;
    unsigned short* base = (unsigned short*)(w + off);  off += (size_t)N_NODES * 128 * 2;
    float* c_ts   = (float*)(w + off);                  off += (size_t)N_NODES * 16 * 4;
    float* scores = (float*)(w + off);                  off += (size_t)N_EDGES * 8 * 4;
    int* counts   = (int*)(w + off);                    off += (size_t)N_NODES * 4;
    int* offsets  = (int*)(w + off);                    off += (size_t)(N_NODES + 1) * 4;
    int* inv      = (int*)(w + off);                    off += (size_t)N_EDGES * 4;
    int* bsum     = (int*)(w + off);                    off += 1024;
    off = alignup(off, 16);
    unsigned short* WnT     = (unsigned short*)(w + off); off += (size_t)3 * 128 * 256 * 2;
    unsigned short* WeaT    = (unsigned short*)(w + off); off += 128 * 64 * 2;
    unsigned short* WetT    = (unsigned short*)(w + off); off += 128 * 64 * 2;
    unsigned short* Wu1T    = (unsigned short*)(w + off); off += 128 * 128 * 2;
    unsigned short* Wu2T    = (unsigned short*)(w + off); off += 128 * 128 * 2;
    unsigned short* WatMidT = (unsigned short*)(w + off); off += 16 * 256 * 2;
    unsigned short* WatTS   = (unsigned short*)(w + off); off += 16 * 128 * 2;
    off = alignup(off, 16);
    unsigned short* ap = (unsigned short*)(w + off);

    k_detect<<<1, 64, 0, stream>>>(nf, eidx, flags);
    k_wprep<<<384, 256, 0, stream>>>(Wn, Wea, Wet, Wup, Wat,
                                     WnT, WeaT, WetT, Wu1T, Wu2T, WatMidT, WatTS,
                                     counts, flags);
    // CSR (k_edge scatters outputs to CSR slots)
    k_hist<<<(N_EDGES + 255) / 256, 256, 0, stream>>>(eidx, counts, flags);
    const int SB = (N_NODES + 255) / 256;
    k_scan1<<<SB, 256, 0, stream>>>(counts, offsets, bsum);
    k_scan2<<<1, 256, 0, stream>>>(bsum, SB);
    k_scan3<<<SB, 256, 0, stream>>>(offsets, bsum, counts);  // also zeroes counts (=fill)
    k_scatter<<<(N_EDGES + 255) / 256, 256, 0, stream>>>(eidx, offsets, counts, inv, flags);

    k_node<<<(N_NODES + 31) / 32, 256, 0, stream>>>(nf, ntyp, WnT, Wu1T, WatTS,
                                                    base, c_ts, flags);
    k_edge<<<N_EDGES / 64, 256, 0, stream>>>(eatt, etyp, eidx, c_ts,
                                             WeaT, WetT, Wu2T, WatMidT,
                                             inv, scores, ap, flags);
    k_aggr4<<<N_NODES / 8, 256, 0, stream>>>(base, scores, ap, offsets, d_out, flags);
}